// Round 12
// baseline (239.617 us; speedup 1.0000x reference)
//
#include <hip/hip_runtime.h>

#pragma clang fp contract(off)

#define NB 8
#define KSEL 6000
#define KPAD 6016
#define PROP 1000
#define NTILE 94
#define RMAX 2048
#define RTILES 32
#define SWORDS 32
#define EQ2CAP 262144

// ws layout (bytes)
#define OFF_HIST1 0u          // 8*4096*4 = 131072
#define OFF_CTRL  131072u     // 512 -> 131584
#define OFF_SEL   131584u     // 8*6016*8 = 385024 -> 516608
#define OFF_EQ2   516608u     // 8*262144*8 = 16777216 -> 17293824
#define OFF_BOX   17293824u   // 8*6016*16 = 770048 -> 18063872
#define OFF_MAT   18063872u   // 8*2048*32*8 = 4194304 -> 22258176
#define MAT_BYTES 4194304ull

struct Ctrl {
  unsigned t1, rem1, selCount, eqCount, total;
  unsigned pad[11];
};

__global__ __launch_bounds__(256) void zero_kernel(unsigned* p, int n) {
  int i = blockIdx.x * 256 + threadIdx.x;
  if (i < n) p[i] = 0u;
}

// Pass 1: 4096-bin histogram of top-12 bits of fg scores; float4 loads (2 elems each).
__global__ __launch_bounds__(256) void hist12_kernel(const float* __restrict__ probs,
                                                     unsigned* __restrict__ hist, int N) {
  __shared__ unsigned lh[4096];
  const int b = blockIdx.y;
  for (int k = threadIdx.x; k < 4096; k += 256) lh[k] = 0u;
  __syncthreads();
  const int start = blockIdx.x * 2048;
  const int end = min(start + 2048, N);
#pragma unroll
  for (int j = 0; j < 4; ++j) {
    const int i = start + j * 512 + (int)threadIdx.x * 2;
    if (i < end) {
      const float4 p2 = *(const float4*)(probs + ((size_t)b * N + i) * 2);
      atomicAdd(&lh[__float_as_uint(p2.y) >> 20], 1u);
      if (i + 1 < end) atomicAdd(&lh[__float_as_uint(p2.w) >> 20], 1u);
    }
  }
  __syncthreads();
  for (int k = threadIdx.x; k < 4096; k += 256) {
    const unsigned v = lh[k];
    if (v) atomicAdd(&hist[b * 4096 + k], v);
  }
}

// one wave per image: descending cumulative scan over 4096 bins -> t1, rem1
__global__ __launch_bounds__(64) void scan12_kernel(const unsigned* __restrict__ hist,
                                                    Ctrl* __restrict__ ctrl) {
  const int b = blockIdx.x;
  const int lane = threadIdx.x;
  const unsigned target = (unsigned)KSEL;
  const unsigned* h = hist + b * 4096;
  const int topbin = 4095 - lane * 64;
  unsigned mysum = 0;
  for (int c = 0; c < 64; c++) mysum += h[topbin - c];
  unsigned cum = mysum;
  for (int off = 1; off < 64; off <<= 1) {
    const unsigned v = __shfl_up(cum, off, 64);
    if (lane >= off) cum += v;
  }
  const unsigned prev = cum - mysum;
  if (prev < target && cum >= target) {
    unsigned c2 = prev;
    for (int c = 0; c < 64; c++) {
      const int bin = topbin - c;
      const unsigned hv = h[bin];
      if (c2 + hv >= target) { ctrl[b].t1 = (unsigned)bin; ctrl[b].rem1 = target - c2; break; }
      c2 += hv;
    }
  }
}

// Pass 2: gt-threshold elements -> sel (order-arbitrary); tie-bin elements -> eq2.
#define EMIT(bitsv, idxv, valid) do {                                                              \
  const bool gt = (valid) && ((bitsv) >> 20) > t1;                                                 \
  const bool eq = (valid) && ((bitsv) >> 20) == t1;                                                \
  const unsigned long long mg = __ballot(gt);                                                      \
  if (mg) {                                                                                        \
    const int leader = __builtin_ctzll(mg);                                                        \
    unsigned base = 0;                                                                             \
    if (lane == leader) base = atomicAdd(&ctrl[b].selCount, (unsigned)__builtin_popcountll(mg));   \
    base = (unsigned)__shfl((int)base, leader, 64);                                                \
    if (gt) {                                                                                      \
      const int rk = __builtin_popcountll(mg & ((1ull << lane) - 1ull));                           \
      const unsigned pos = base + (unsigned)rk;                                                    \
      if (pos < (unsigned)KPAD)                                                                    \
        sel[b * KPAD + pos] = ((unsigned long long)(bitsv) << 32) | (unsigned)(idxv);              \
    }                                                                                              \
  }                                                                                                \
  const unsigned long long me = __ballot(eq);                                                      \
  if (me) {                                                                                        \
    const int leader = __builtin_ctzll(me);                                                        \
    unsigned base = 0;                                                                             \
    if (lane == leader) base = atomicAdd(&ctrl[b].eqCount, (unsigned)__builtin_popcountll(me));    \
    base = (unsigned)__shfl((int)base, leader, 64);                                                \
    if (eq) {                                                                                      \
      const int rk = __builtin_popcountll(me & ((1ull << lane) - 1ull));                           \
      const unsigned pos = base + (unsigned)rk;                                                    \
      if (pos < (unsigned)EQ2CAP)                                                                  \
        eq2[(size_t)b * EQ2CAP + pos] = ((unsigned long long)(bitsv) << 32) | (unsigned)(idxv);    \
    }                                                                                              \
  }                                                                                                \
} while (0)

__global__ __launch_bounds__(256) void compact2_kernel(const float* __restrict__ probs,
                                                       Ctrl* __restrict__ ctrl,
                                                       unsigned long long* __restrict__ sel,
                                                       unsigned long long* __restrict__ eq2, int N) {
  const int b = blockIdx.y;
  const unsigned t1 = ctrl[b].t1;
  const int start = blockIdx.x * 2048;
  const int end = min(start + 2048, N);
  const int lane = threadIdx.x & 63;
#pragma unroll
  for (int j = 0; j < 4; ++j) {
    const int i = start + j * 512 + (int)threadIdx.x * 2;
    unsigned bits0 = 0u, bits1 = 0u;
    bool v0 = false, v1 = false;
    if (i < end) {
      const float4 p2 = *(const float4*)(probs + ((size_t)b * N + i) * 2);
      bits0 = __float_as_uint(p2.y); v0 = true;
      if (i + 1 < end) { bits1 = __float_as_uint(p2.w); v1 = true; }
    }
    EMIT(bits0, i, v0);
    EMIT(bits1, i + 1, v1);
  }
}

// wave-0 scans over a 1024-bin LDS histogram
__device__ inline void scan1024_desc(const unsigned* h, unsigned target, int lane,
                                     unsigned* outBin, unsigned* outRem) {
  const int topbin = 1023 - lane * 16;
  unsigned mysum = 0;
  for (int c = 0; c < 16; ++c) mysum += h[topbin - c];
  unsigned cum = mysum;
  for (int off = 1; off < 64; off <<= 1) {
    const unsigned v = __shfl_up(cum, off, 64);
    if (lane >= off) cum += v;
  }
  const unsigned prev = cum - mysum;
  if (prev < target && cum >= target) {
    unsigned c2 = prev;
    for (int c = 0; c < 16; ++c) {
      const int bin = topbin - c;
      const unsigned hv = h[bin];
      if (c2 + hv >= target) { *outBin = (unsigned)bin; *outRem = target - c2; break; }
      c2 += hv;
    }
  }
}
__device__ inline void scan1024_asc(const unsigned* h, unsigned target, int lane,
                                    unsigned* outBin, unsigned* outRem) {
  const int botbin = lane * 16;
  unsigned mysum = 0;
  for (int c = 0; c < 16; ++c) mysum += h[botbin + c];
  unsigned cum = mysum;
  for (int off = 1; off < 64; off <<= 1) {
    const unsigned v = __shfl_up(cum, off, 64);
    if (lane >= off) cum += v;
  }
  const unsigned prev = cum - mysum;
  if (prev < target && cum >= target) {
    unsigned c2 = prev;
    for (int c = 0; c < 16; ++c) {
      const int bin = botbin + c;
      const unsigned hv = h[bin];
      if (c2 + hv >= target) { *outBin = (unsigned)bin; *outRem = target - c2; break; }
      c2 += hv;
    }
  }
}

// Tie resolution within the t1 bin: radix on bits[19:10], bits[9:0], then ascending idx>>8,
// then <=256-entry rank-select on exact ties. Selection order == (bits desc, idx asc) exactly.
__global__ __launch_bounds__(256) void eqres2_kernel(Ctrl* __restrict__ ctrl,
                                                     const unsigned long long* __restrict__ eq2,
                                                     unsigned long long* __restrict__ sel) {
  __shared__ unsigned h1[1024];
  __shared__ unsigned s_binA, s_remA, s_binB, s_remB, s_binC, s_remC;
  __shared__ unsigned s_pos, s_lcnt;
  __shared__ unsigned s_lidx[256];
  const int b = blockIdx.x;
  const int tid = threadIdx.x, lane = tid & 63, wv = tid >> 6;
  unsigned cnt = ctrl[b].eqCount; if (cnt > (unsigned)EQ2CAP) cnt = EQ2CAP;
  const unsigned rem1 = ctrl[b].rem1;
  const unsigned long long* E = eq2 + (size_t)b * EQ2CAP;

  // level A: bits[19:10], descending
  for (int k = tid; k < 1024; k += 256) h1[k] = 0u;
  __syncthreads();
  for (unsigned k = tid; k < cnt; k += 256)
    atomicAdd(&h1[((unsigned)(E[k] >> 32) >> 10) & 1023u], 1u);
  __syncthreads();
  if (wv == 0) scan1024_desc(h1, rem1, lane, &s_binA, &s_remA);
  __syncthreads();
  const unsigned binA = s_binA, remA = s_remA;
  __syncthreads();
  // level B: bits[9:0] within binA, descending
  for (int k = tid; k < 1024; k += 256) h1[k] = 0u;
  __syncthreads();
  for (unsigned k = tid; k < cnt; k += 256) {
    const unsigned bits = (unsigned)(E[k] >> 32);
    if (((bits >> 10) & 1023u) == binA) atomicAdd(&h1[bits & 1023u], 1u);
  }
  __syncthreads();
  if (wv == 0) scan1024_desc(h1, remA, lane, &s_binB, &s_remB);
  __syncthreads();
  const unsigned binB = s_binB, remB = s_remB;
  const unsigned key20 = (binA << 10) | binB;
  __syncthreads();
  // level C: idx>>8 among exact-threshold bits, ascending (lower index preferred)
  for (int k = tid; k < 1024; k += 256) h1[k] = 0u;
  __syncthreads();
  for (unsigned k = tid; k < cnt; k += 256) {
    const unsigned long long r = E[k];
    if (((unsigned)(r >> 32) & 0xFFFFFu) == key20) atomicAdd(&h1[((unsigned)r) >> 8], 1u);
  }
  __syncthreads();
  if (wv == 0) scan1024_asc(h1, remB, lane, &s_binC, &s_remC);
  if (tid == 0) { s_pos = ctrl[b].selCount; s_lcnt = 0u; }
  __syncthreads();
  const unsigned binC = s_binC, remC = s_remC;
  // write pass
  for (unsigned k0 = 0; k0 < cnt; k0 += 256) {
    const unsigned k = k0 + tid;
    bool take = false, lst = false;
    unsigned long long rec = 0ull;
    if (k < cnt) {
      rec = E[k];
      const unsigned bits = (unsigned)(rec >> 32);
      const unsigned k20 = bits & 0xFFFFFu;
      const unsigned idx = (unsigned)rec;
      if ((k20 >> 10) > binA) take = true;
      else if ((k20 >> 10) == binA && (k20 & 1023u) > binB) take = true;
      else if (k20 == key20) {
        if ((idx >> 8) < binC) take = true;
        else if ((idx >> 8) == binC) lst = true;
      }
    }
    const unsigned long long mt = __ballot(take);
    if (mt) {
      const int leader = __builtin_ctzll(mt);
      unsigned base = 0;
      if (lane == leader) base = atomicAdd(&s_pos, (unsigned)__builtin_popcountll(mt));
      base = (unsigned)__shfl((int)base, leader, 64);
      if (take) {
        const int rk = __builtin_popcountll(mt & ((1ull << lane) - 1ull));
        const unsigned p = base + (unsigned)rk;
        if (p < (unsigned)KPAD) sel[b * KPAD + p] = rec;
      }
    }
    if (lst) {
      const unsigned p = atomicAdd(&s_lcnt, 1u);
      if (p < 256u) s_lidx[p] = (unsigned)rec;
    }
  }
  __syncthreads();
  const unsigned lcnt = (s_lcnt < 256u) ? s_lcnt : 256u;  // bin C holds <=256 distinct indices
  const unsigned long long thrHi = ((unsigned long long)((ctrl[b].t1 << 20) | key20)) << 32;
  if (tid < (int)lcnt) {
    const unsigned my = s_lidx[tid];
    unsigned rk = 0;
    for (unsigned f = 0; f < lcnt; ++f) rk += (s_lidx[f] < my) ? 1u : 0u;
    if (rk < remC) {
      const unsigned p = atomicAdd(&s_pos, 1u);
      if (p < (unsigned)KPAD) sel[b * KPAD + p] = thrHi | (unsigned long long)my;
    }
  }
  __syncthreads();
  if (tid == 0) ctrl[b].total = s_pos;
}

// Pairwise rank + fused decode. key = (scorebits<<32) | ~idx; rank = #{keys > mine}.
__global__ __launch_bounds__(256) void rank_kernel(const Ctrl* __restrict__ ctrl,
                                                   const unsigned long long* __restrict__ sel,
                                                   const float* __restrict__ anchors,
                                                   const float* __restrict__ bbox,
                                                   float4* __restrict__ boxes, int N) {
  const int b = blockIdx.x & 7;
  const int it = blockIdx.x >> 3;    // 0..93
  const int tid = threadIdx.x;
  const int wv = tid >> 6, lane = tid & 63;
  __shared__ unsigned long long skey[KPAD];   // 48128 B
  __shared__ unsigned scnt[4][64];
  int total = (int)ctrl[b].total; if (total > KSEL) total = KSEL;
  for (int i = tid; i < KPAD; i += 256) {
    unsigned long long kp = 0ull;
    if (i < total) {
      const unsigned long long e = sel[b * KPAD + i];
      kp = (e & 0xFFFFFFFF00000000ull) | (unsigned long long)(0xFFFFFFFFu - (unsigned)e);
    }
    skey[i] = kp;
  }
  __syncthreads();
  const int me = it * 64 + lane;
  const unsigned long long myk = skey[me];
  const int chunk = KPAD / 4;
  const int lo = wv * chunk;
  unsigned cnt = 0;
#pragma unroll 8
  for (int c = 0; c < chunk; ++c) cnt += (skey[lo + c] > myk) ? 1u : 0u;
  scnt[wv][lane] = cnt;
  __syncthreads();
  if (wv == 0 && me < total) {
    const unsigned rank = scnt[0][lane] + scnt[1][lane] + scnt[2][lane] + scnt[3][lane];
    unsigned idx = 0xFFFFFFFFu - (unsigned)myk;
    if (idx >= (unsigned)N) idx = 0;
    const float4 A = ((const float4*)anchors)[(size_t)b * N + idx];
    const float4 R = ((const float4*)bbox)[(size_t)b * N + idx];
    const float d0 = R.x * 0.1f, d1 = R.y * 0.1f, d2 = R.z * 0.2f, d3 = R.w * 0.2f;
    const float h = A.z - A.x;
    const float w = A.w - A.y;
    const float cy = A.x + 0.5f * h + d0 * h;
    const float cx = A.y + 0.5f * w + d1 * w;
    const float e2 = (float)exp((double)d2);  // correctly-rounded f32 exp
    const float e3 = (float)exp((double)d3);
    const float h2 = h * e2;
    const float w2 = w * e3;
    float y1 = cy - 0.5f * h2;
    float x1 = cx - 0.5f * w2;
    float y2 = y1 + h2;
    float x2 = x1 + w2;
    y1 = fminf(fmaxf(y1, 0.0f), 1.0f);
    x1 = fminf(fmaxf(x1, 0.0f), 1.0f);
    y2 = fminf(fmaxf(y2, 0.0f), 1.0f);
    x2 = fminf(fmaxf(x2, 0.0f), 1.0f);
    boxes[b * KPAD + rank] = make_float4(y1, x1, y2, x2);
  }
}

// ---- 2048x2048 upper-triangular suppression matrix, row-major (unchanged, verified) ----
__global__ __launch_bounds__(256) void suppmat_kernel(const float4* __restrict__ boxes,
                                                      unsigned long long* __restrict__ mat) {
  const int b = blockIdx.x & 7;
  const int it = blockIdx.x >> 3;       // row tile 0..RTILES-1
  const int wv = threadIdx.x >> 6;
  const int lane = threadIdx.x & 63;
  const float4* gbox = boxes + b * KPAD;
  __shared__ float4 srow[64];
  __shared__ float sarea[64];
  __shared__ unsigned long long wbuf[64][SWORDS];   // 16 KiB
  if (threadIdx.x < 64) {
    const float4 v = gbox[it * 64 + threadIdx.x];
    srow[threadIdx.x] = v;
    sarea[threadIdx.x] = (v.z - v.x) * (v.w - v.y);
  }
  __syncthreads();
  float4 rb[16]; float rba[16];
#pragma unroll
  for (int k = 0; k < 16; ++k) { rb[k] = srow[wv * 16 + k]; rba[k] = sarea[wv * 16 + k]; }
  const double M = 0.7000000178813934326171875;
  for (int jt = it; jt < SWORDS; ++jt) {
    const int c = jt * 64 + lane;
    const float4 cv = gbox[c];
    const float ca = (cv.z - cv.x) * (cv.w - cv.y);
#pragma unroll
    for (int k = 0; k < 16; ++k) {
      const int i = it * 64 + wv * 16 + k;
      const float4 hb = rb[k];
      const float ha = rba[k];
      const float iy1 = fmaxf(hb.x, cv.x);
      const float ix1 = fmaxf(hb.y, cv.y);
      const float iy2 = fminf(hb.z, cv.z);
      const float ix2 = fminf(hb.w, cv.w);
      const float dy = fmaxf(iy2 - iy1, 0.0f);
      const float dx = fmaxf(ix2 - ix1, 0.0f);
      const float inter = dy * dx;
      const float denom = ha + ca - inter + 1e-12f;
      const bool s = (c > i) && ((double)inter >= M * (double)denom);
      const unsigned long long w = __ballot(s);
      if (lane == 0) wbuf[wv * 16 + k][jt] = w;
    }
  }
  __syncthreads();
  const int nw = SWORDS - it;
  unsigned long long* obase = mat + ((size_t)b * RMAX + (size_t)it * 64) * SWORDS;
  for (int q = threadIdx.x; q < 64 * nw; q += 256) {
    const int r = q / nw;
    const int k = q - r * nw;
    obase[(size_t)r * SWORDS + it + k] = wbuf[r][it + k];
  }
}

// Chunked exact greedy NMS with SPARSE replay (unchanged, verified round 11).
__global__ __launch_bounds__(64) void nmsscan_kernel(const Ctrl* __restrict__ ctrl,
                                                     const float4* __restrict__ boxes,
                                                     const unsigned long long* __restrict__ mat,
                                                     float* __restrict__ out) {
  const int b = blockIdx.x;
  const int lane = threadIdx.x;
  int total = (int)ctrl[b].total; if (total > KSEL) total = KSEL;
  const unsigned long long* rmat = mat + (size_t)b * RMAX * SWORDS;  // [row][w]
  const float4* gbox = boxes + b * KPAD;
  float4* outv = (float4*)(out + (size_t)b * PROP * 4);
  __shared__ int s_sel[PROP];
  __shared__ float4 s_hbox[PROP];
  const int lim = (total < RMAX) ? total : RMAX;
  const int nchunks = (lim + 63) >> 6;
  const bool wlane = lane < SWORDS;
  unsigned long long r0 = 0ull;     // removed word `lane` (lanes 0..SWORDS-1)
  int nsel = 0;

  unsigned long long diagN = (lane < lim) ? rmat[(size_t)lane * SWORDS] : 0ull;
  for (int c = 0; c < nchunks && nsel < PROP; ++c) {
    const int base = c << 6;
    const int n = ((lim - base) < 64) ? (lim - base) : 64;
    const unsigned long long diag = diagN;
    const int nb2 = base + 64;
    diagN = ((c + 1) < nchunks && (nb2 + lane) < lim)
              ? rmat[(size_t)(nb2 + lane) * SWORDS + (c + 1)] : 0ull;
    unsigned long long aw = ~__shfl(r0, c, 64);
    if (n < 64) aw &= ((1ull << n) - 1ull);
    unsigned long long S = __ballot(diag != 0ull);
    while (S) {
      const int s = __builtin_ctzll(S);
      S &= S - 1ull;
      const unsigned long long cm = __shfl(diag, s, 64);
      if ((aw >> s) & 1ull) aw &= ~cm;
    }
    unsigned long long acc = aw;
    const int need = PROP - nsel;
    int na = __popcll(acc);
    if (na > need) {
      unsigned long long t2 = acc, a2 = 0ull;
      for (int c2 = 0; c2 < need; ++c2) { a2 |= t2 & (0ull - t2); t2 &= t2 - 1ull; }
      acc = a2; na = need;
    }
    if ((acc >> lane) & 1ull) {
      const int r = __popcll(acc & ((1ull << lane) - 1ull));
      s_sel[nsel + r] = base + lane;
    }
    nsel += na;
    if (nsel >= PROP || c + 1 >= nchunks) continue;
    if (wlane) {
      const unsigned long long* rowbase = rmat + (size_t)base * SWORDS + lane;
      unsigned long long o = 0ull;
#pragma unroll
      for (int r = 0; r < 64; ++r) {
        const unsigned long long v = rowbase[(size_t)r * SWORDS];
        o |= (((acc >> r) & 1ull) ? v : 0ull);
      }
      r0 |= o;
    }
  }
  if (nsel < PROP && total > lim) {
    for (int k = lane; k < nsel; k += 64) s_hbox[k] = gbox[s_sel[k]];
    __syncthreads();
    const double M = 0.7000000178813934326171875;
    for (int i2 = lim; i2 < total && nsel < PROP; ++i2) {
      const float4 v = gbox[i2];
      const float a = (v.z - v.x) * (v.w - v.y);
      bool supp = false;
      for (int h = lane; h < nsel; h += 64) {
        const float4 hb = s_hbox[h];
        const float ha = (hb.z - hb.x) * (hb.w - hb.y);
        const float iy1 = fmaxf(hb.x, v.x);
        const float ix1 = fmaxf(hb.y, v.y);
        const float iy2 = fminf(hb.z, v.z);
        const float ix2 = fminf(hb.w, v.w);
        const float dy = fmaxf(iy2 - iy1, 0.0f);
        const float dx = fmaxf(ix2 - ix1, 0.0f);
        const float inter = dy * dx;
        const float denom = ha + a - inter + 1e-12f;
        if ((double)inter >= M * (double)denom) { supp = true; break; }
      }
      if (!__any(supp)) {
        if (lane == 0) { s_sel[nsel] = i2; s_hbox[nsel] = v; }
        ++nsel;
      }
    }
  }
  __syncthreads();
  for (int k = lane; k < PROP; k += 64)
    outv[k] = (k < nsel) ? gbox[s_sel[k]] : make_float4(0.f, 0.f, 0.f, 0.f);
}

// ---- fallback windowed NMS (boxes-only) for small ws ----
__global__ __launch_bounds__(1024) void nms_kernel(const float4* __restrict__ boxes, float* __restrict__ out) {
  const int b = blockIdx.x;
  const int tid = threadIdx.x;
  const int lane = tid & 63;
  const float4* gbox = boxes + b * KPAD;
  float* outB = out + b * (PROP * 4);
  __shared__ unsigned long long smask[94];
  __shared__ int s_widx[64];
  __shared__ float4 s_wbox[64];
  __shared__ float s_wha[64];
  __shared__ int s_cnt, s_nAcc, s_total, s_cursor;
  for (int k = tid; k < 94; k += 1024)
    smask[k] = (k == 93) ? ((1ull << 48) - 1ull) : ~0ull;
  if (tid == 0) { s_cursor = 0; s_total = 0; }
  __syncthreads();
  const double M = 0.7000000178813934326171875;
  for (int round = 0; round < PROP; ++round) {
    if (tid == 0) {
      int cnt = 0;
      const int cur = s_cursor;
      int w = cur >> 6;
      unsigned long long word = (w < 94) ? (smask[w] & (~0ull << (cur & 63))) : 0ull;
      while (cnt < 64) {
        while (word == 0ull && ++w < 94) word = smask[w];
        if (w >= 94) break;
        const int bit = __builtin_ctzll(word);
        word &= word - 1ull;
        s_widx[cnt++] = (w << 6) | bit;
      }
      s_cnt = cnt;
      s_cursor = cnt ? (s_widx[cnt - 1] + 1) : KSEL;
    }
    __syncthreads();
    const int cnt = s_cnt;
    const int tailStart = s_cursor;
    if (cnt == 0) break;
    if (tid < 64) {
      const int j = (lane < cnt) ? s_widx[lane] : -1;
      float4 v = make_float4(0.f, 0.f, 0.f, 0.f);
      if (j >= 0) v = gbox[j];
      const float a = (v.z - v.x) * (v.w - v.y);
      const int totalOld = s_total;
      unsigned long long aliveW = __ballot(j >= 0);
      unsigned long long acc = 0ull;
      for (int i = 0; i < 64; ++i) {
        const float hx = __shfl(v.x, i), hy = __shfl(v.y, i);
        const float hz = __shfl(v.z, i), hw = __shfl(v.w, i);
        const float ha = __shfl(a, i);
        bool s = false;
        if (j >= 0 && lane > i) {
          const float iy1 = fmaxf(hx, v.x);
          const float ix1 = fmaxf(hy, v.y);
          const float iy2 = fminf(hz, v.z);
          const float ix2 = fminf(hw, v.w);
          const float dy = fmaxf(iy2 - iy1, 0.0f);
          const float dx = fmaxf(ix2 - ix1, 0.0f);
          const float inter = dy * dx;
          const float denom = ha + a - inter + 1e-12f;
          s = ((double)inter >= M * (double)denom);
        }
        const unsigned long long m = __ballot(s);
        if (aliveW & (1ull << i)) { acc |= 1ull << i; aliveW &= ~m; }
      }
      const int need = PROP - totalOld;
      int na = __popcll(acc);
      if (na > need) {
        unsigned long long t = acc, a2 = 0ull;
        for (int c2 = 0; c2 < need; ++c2) { a2 |= t & (0ull - t); t &= t - 1ull; }
        acc = a2; na = need;
      }
      if ((acc >> lane) & 1ull) {
        const int r = __popcll(acc & ((1ull << lane) - 1ull));
        float* o = outB + (size_t)(totalOld + r) * 4;
        o[0] = v.x; o[1] = v.y; o[2] = v.z; o[3] = v.w;
        s_wbox[r] = v; s_wha[r] = a;
      }
      if (lane == 0) { s_nAcc = na; s_total = totalOld + na; }
      if (j >= 0) atomicAnd(&smask[j >> 6], ~(1ull << (j & 63)));
    }
    __syncthreads();
    const int total = s_total;
    const int nAcc = s_nAcc;
    if (total >= PROP) break;
    for (int j = tailStart + tid; j < KSEL; j += 1024) {
      if (!((smask[j >> 6] >> (j & 63)) & 1ull)) continue;
      const float4 v = gbox[j];
      const float a = (v.z - v.x) * (v.w - v.y);
      bool supp = false;
      for (int r = 0; r < nAcc; ++r) {
        const float4 hb = s_wbox[r];
        const float ha = s_wha[r];
        const float iy1 = fmaxf(hb.x, v.x);
        const float ix1 = fmaxf(hb.y, v.y);
        const float iy2 = fminf(hb.z, v.z);
        const float ix2 = fminf(hb.w, v.w);
        const float dy = fmaxf(iy2 - iy1, 0.0f);
        const float dx = fmaxf(ix2 - ix1, 0.0f);
        const float inter = dy * dx;
        const float denom = ha + a - inter + 1e-12f;
        if ((double)inter >= M * (double)denom) { supp = true; break; }
      }
      if (supp) atomicAnd(&smask[j >> 6], ~(1ull << (j & 63)));
    }
    __syncthreads();
  }
  const int written = s_total;
  for (int u = written * 4 + tid; u < PROP * 4; u += 1024) outB[u] = 0.0f;
}

extern "C" void kernel_launch(void* const* d_in, const int* in_sizes, int n_in,
                              void* d_out, int out_size, void* d_ws, size_t ws_size,
                              hipStream_t stream) {
  (void)n_in; (void)out_size;
  const float* probs = (const float*)d_in[0];
  const float* bbox = (const float*)d_in[1];
  const float* anchors = (const float*)d_in[2];
  float* out = (float*)d_out;
  char* ws = (char*)d_ws;
  const int N = in_sizes[0] / (NB * 2);  // 261888

  unsigned* hist1 = (unsigned*)(ws + OFF_HIST1);
  Ctrl* ctrl = (Ctrl*)(ws + OFF_CTRL);
  unsigned long long* sel = (unsigned long long*)(ws + OFF_SEL);
  unsigned long long* eq2 = (unsigned long long*)(ws + OFF_EQ2);
  float4* boxes = (float4*)(ws + OFF_BOX);
  unsigned long long* mat = (unsigned long long*)(ws + OFF_MAT);

  const int zeroN = (int)((OFF_SEL - OFF_HIST1) / 4);  // hist1 + ctrl
  zero_kernel<<<dim3((zeroN + 255) / 256), dim3(256), 0, stream>>>((unsigned*)ws, zeroN);

  const int gx = (N + 2047) / 2048;      // 128
  hist12_kernel<<<dim3(gx, NB), dim3(256), 0, stream>>>(probs, hist1, N);
  scan12_kernel<<<dim3(NB), dim3(64), 0, stream>>>(hist1, ctrl);
  compact2_kernel<<<dim3(gx, NB), dim3(256), 0, stream>>>(probs, ctrl, sel, eq2, N);
  eqres2_kernel<<<dim3(NB), dim3(256), 0, stream>>>(ctrl, eq2, sel);
  rank_kernel<<<dim3(NTILE * NB), dim3(256), 0, stream>>>(ctrl, sel, anchors, bbox, boxes, N);

  if (ws_size >= (size_t)OFF_MAT + MAT_BYTES) {
    suppmat_kernel<<<dim3(RTILES * NB), dim3(256), 0, stream>>>(boxes, mat);
    nmsscan_kernel<<<dim3(NB), dim3(64), 0, stream>>>(ctrl, boxes, mat, out);
  } else {
    nms_kernel<<<dim3(NB), dim3(1024), 0, stream>>>(boxes, out);
  }
}

// Round 13
// 177.961 us; speedup vs baseline: 1.3465x; 1.3465x over previous
//
#include <hip/hip_runtime.h>

#pragma clang fp contract(off)

#define NB 8
#define KSEL 6000
#define KPAD 6016
#define PROP 1000
#define NTILE 94
#define RMAX 2048
#define RTILES 32
#define SWORDS 32
#define EQ2CAP 262144

// ws layout (bytes)
#define OFF_HIST1 0u          // 8*4096*4 = 131072
#define OFF_CTRL  131072u     // 512 -> 131584
#define OFF_SEL   131584u     // 8*6016*8 = 385024 -> 516608
#define OFF_EQ2   516608u     // 8*262144*8 = 16777216 -> 17293824
#define OFF_BOX   17293824u   // 8*6016*16 = 770048 -> 18063872
#define OFF_MAT   18063872u   // 8*2048*32*8 = 4194304 -> 22258176
#define MAT_BYTES 4194304ull

struct Ctrl {
  unsigned t1, rem1, selCount, eqCount, total;
  unsigned pad[11];
};

__global__ __launch_bounds__(256) void zero_kernel(unsigned* p, int n) {
  int i = blockIdx.x * 256 + threadIdx.x;
  if (i < n) p[i] = 0u;
}

// Pass 1: 4096-bin histogram of top-12 bits of fg scores; float4 loads (2 elems each).
__global__ __launch_bounds__(256) void hist12_kernel(const float* __restrict__ probs,
                                                     unsigned* __restrict__ hist, int N) {
  __shared__ unsigned lh[4096];
  const int b = blockIdx.y;
  for (int k = threadIdx.x; k < 4096; k += 256) lh[k] = 0u;
  __syncthreads();
  const int start = blockIdx.x * 2048;
  const int end = min(start + 2048, N);
#pragma unroll
  for (int j = 0; j < 4; ++j) {
    const int i = start + j * 512 + (int)threadIdx.x * 2;
    if (i < end) {
      const float4 p2 = *(const float4*)(probs + ((size_t)b * N + i) * 2);
      atomicAdd(&lh[__float_as_uint(p2.y) >> 20], 1u);
      if (i + 1 < end) atomicAdd(&lh[__float_as_uint(p2.w) >> 20], 1u);
    }
  }
  __syncthreads();
  for (int k = threadIdx.x; k < 4096; k += 256) {
    const unsigned v = lh[k];
    if (v) atomicAdd(&hist[b * 4096 + k], v);
  }
}

// one wave per image: descending cumulative scan over 4096 bins -> t1, rem1
__global__ __launch_bounds__(64) void scan12_kernel(const unsigned* __restrict__ hist,
                                                    Ctrl* __restrict__ ctrl) {
  const int b = blockIdx.x;
  const int lane = threadIdx.x;
  const unsigned target = (unsigned)KSEL;
  const unsigned* h = hist + b * 4096;
  const int topbin = 4095 - lane * 64;
  unsigned mysum = 0;
  for (int c = 0; c < 64; c++) mysum += h[topbin - c];
  unsigned cum = mysum;
  for (int off = 1; off < 64; off <<= 1) {
    const unsigned v = __shfl_up(cum, off, 64);
    if (lane >= off) cum += v;
  }
  const unsigned prev = cum - mysum;
  if (prev < target && cum >= target) {
    unsigned c2 = prev;
    for (int c = 0; c < 64; c++) {
      const int bin = topbin - c;
      const unsigned hv = h[bin];
      if (c2 + hv >= target) { ctrl[b].t1 = (unsigned)bin; ctrl[b].rem1 = target - c2; break; }
      c2 += hv;
    }
  }
}

// Pass 2: block-aggregated compaction. Hits staged in LDS (gt from front, eq from back;
// combined <= 2048 = block element count), ONE global atomicAdd per block per list,
// then coalesced LDS->global copy. Order within sel/eq2 is arbitrary (re-sorted later).
__global__ __launch_bounds__(256) void compact2_kernel(const float* __restrict__ probs,
                                                       Ctrl* __restrict__ ctrl,
                                                       unsigned long long* __restrict__ sel,
                                                       unsigned long long* __restrict__ eq2, int N) {
  __shared__ unsigned long long buf[2048];   // 16 KiB
  __shared__ unsigned s_ngt, s_neq, s_gbase, s_ebase;
  const int b = blockIdx.y;
  const int tid = threadIdx.x;
  const unsigned t1 = ctrl[b].t1;
  const int start = blockIdx.x * 2048;
  const int end = min(start + 2048, N);
  if (tid == 0) { s_ngt = 0u; s_neq = 0u; }
  __syncthreads();
  // batched loads (ILP), then classify into LDS lists via cheap LDS atomics
  unsigned bits[8];
  int idxs[8];
#pragma unroll
  for (int j = 0; j < 4; ++j) {
    const int i = start + j * 512 + tid * 2;
    float4 p2 = make_float4(0.f, 0.f, 0.f, 0.f);
    if (i < end) p2 = *(const float4*)(probs + ((size_t)b * N + i) * 2);
    bits[j * 2]     = (i < end) ? __float_as_uint(p2.y) : 0u;
    idxs[j * 2]     = (i < end) ? i : -1;
    bits[j * 2 + 1] = (i + 1 < end) ? __float_as_uint(p2.w) : 0u;
    idxs[j * 2 + 1] = (i + 1 < end) ? (i + 1) : -1;
  }
#pragma unroll
  for (int e = 0; e < 8; ++e) {
    if (idxs[e] >= 0) {
      const unsigned top = bits[e] >> 20;
      if (top > t1) {
        const unsigned p = atomicAdd(&s_ngt, 1u);
        buf[p] = ((unsigned long long)bits[e] << 32) | (unsigned)idxs[e];
      } else if (top == t1) {
        const unsigned p = atomicAdd(&s_neq, 1u);
        buf[2047 - p] = ((unsigned long long)bits[e] << 32) | (unsigned)idxs[e];
      }
    }
  }
  __syncthreads();
  const unsigned ngt = s_ngt, neq = s_neq;
  if (tid == 0 && ngt) s_gbase = atomicAdd(&ctrl[b].selCount, ngt);
  if (tid == 1 && neq) s_ebase = atomicAdd(&ctrl[b].eqCount, neq);
  __syncthreads();
  for (unsigned k = tid; k < ngt; k += 256) {
    const unsigned p = s_gbase + k;
    if (p < (unsigned)KPAD) sel[b * KPAD + p] = buf[k];
  }
  for (unsigned k = tid; k < neq; k += 256) {
    const unsigned p = s_ebase + k;
    if (p < (unsigned)EQ2CAP) eq2[(size_t)b * EQ2CAP + p] = buf[2047 - k];
  }
}

// wave-0 scans over a 1024-bin LDS histogram
__device__ inline void scan1024_desc(const unsigned* h, unsigned target, int lane,
                                     unsigned* outBin, unsigned* outRem) {
  const int topbin = 1023 - lane * 16;
  unsigned mysum = 0;
  for (int c = 0; c < 16; ++c) mysum += h[topbin - c];
  unsigned cum = mysum;
  for (int off = 1; off < 64; off <<= 1) {
    const unsigned v = __shfl_up(cum, off, 64);
    if (lane >= off) cum += v;
  }
  const unsigned prev = cum - mysum;
  if (prev < target && cum >= target) {
    unsigned c2 = prev;
    for (int c = 0; c < 16; ++c) {
      const int bin = topbin - c;
      const unsigned hv = h[bin];
      if (c2 + hv >= target) { *outBin = (unsigned)bin; *outRem = target - c2; break; }
      c2 += hv;
    }
  }
}
__device__ inline void scan1024_asc(const unsigned* h, unsigned target, int lane,
                                    unsigned* outBin, unsigned* outRem) {
  const int botbin = lane * 16;
  unsigned mysum = 0;
  for (int c = 0; c < 16; ++c) mysum += h[botbin + c];
  unsigned cum = mysum;
  for (int off = 1; off < 64; off <<= 1) {
    const unsigned v = __shfl_up(cum, off, 64);
    if (lane >= off) cum += v;
  }
  const unsigned prev = cum - mysum;
  if (prev < target && cum >= target) {
    unsigned c2 = prev;
    for (int c = 0; c < 16; ++c) {
      const int bin = botbin + c;
      const unsigned hv = h[bin];
      if (c2 + hv >= target) { *outBin = (unsigned)bin; *outRem = target - c2; break; }
      c2 += hv;
    }
  }
}

// Tie resolution within the t1 bin: radix on bits[19:10], bits[9:0], then ascending idx>>8,
// then <=256-entry rank-select on exact ties. Selection order == (bits desc, idx asc) exactly.
__global__ __launch_bounds__(256) void eqres2_kernel(Ctrl* __restrict__ ctrl,
                                                     const unsigned long long* __restrict__ eq2,
                                                     unsigned long long* __restrict__ sel) {
  __shared__ unsigned h1[1024];
  __shared__ unsigned s_binA, s_remA, s_binB, s_remB, s_binC, s_remC;
  __shared__ unsigned s_pos, s_lcnt;
  __shared__ unsigned s_lidx[256];
  const int b = blockIdx.x;
  const int tid = threadIdx.x, lane = tid & 63, wv = tid >> 6;
  unsigned cnt = ctrl[b].eqCount; if (cnt > (unsigned)EQ2CAP) cnt = EQ2CAP;
  const unsigned rem1 = ctrl[b].rem1;
  const unsigned long long* E = eq2 + (size_t)b * EQ2CAP;

  // level A: bits[19:10], descending
  for (int k = tid; k < 1024; k += 256) h1[k] = 0u;
  __syncthreads();
  for (unsigned k = tid; k < cnt; k += 256)
    atomicAdd(&h1[((unsigned)(E[k] >> 32) >> 10) & 1023u], 1u);
  __syncthreads();
  if (wv == 0) scan1024_desc(h1, rem1, lane, &s_binA, &s_remA);
  __syncthreads();
  const unsigned binA = s_binA, remA = s_remA;
  __syncthreads();
  // level B: bits[9:0] within binA, descending
  for (int k = tid; k < 1024; k += 256) h1[k] = 0u;
  __syncthreads();
  for (unsigned k = tid; k < cnt; k += 256) {
    const unsigned bits = (unsigned)(E[k] >> 32);
    if (((bits >> 10) & 1023u) == binA) atomicAdd(&h1[bits & 1023u], 1u);
  }
  __syncthreads();
  if (wv == 0) scan1024_desc(h1, remA, lane, &s_binB, &s_remB);
  __syncthreads();
  const unsigned binB = s_binB, remB = s_remB;
  const unsigned key20 = (binA << 10) | binB;
  __syncthreads();
  // level C: idx>>8 among exact-threshold bits, ascending (lower index preferred)
  for (int k = tid; k < 1024; k += 256) h1[k] = 0u;
  __syncthreads();
  for (unsigned k = tid; k < cnt; k += 256) {
    const unsigned long long r = E[k];
    if (((unsigned)(r >> 32) & 0xFFFFFu) == key20) atomicAdd(&h1[((unsigned)r) >> 8], 1u);
  }
  __syncthreads();
  if (wv == 0) scan1024_asc(h1, remB, lane, &s_binC, &s_remC);
  if (tid == 0) { s_pos = ctrl[b].selCount; s_lcnt = 0u; }
  __syncthreads();
  const unsigned binC = s_binC, remC = s_remC;
  // write pass
  for (unsigned k0 = 0; k0 < cnt; k0 += 256) {
    const unsigned k = k0 + tid;
    bool take = false, lst = false;
    unsigned long long rec = 0ull;
    if (k < cnt) {
      rec = E[k];
      const unsigned bits = (unsigned)(rec >> 32);
      const unsigned k20 = bits & 0xFFFFFu;
      const unsigned idx = (unsigned)rec;
      if ((k20 >> 10) > binA) take = true;
      else if ((k20 >> 10) == binA && (k20 & 1023u) > binB) take = true;
      else if (k20 == key20) {
        if ((idx >> 8) < binC) take = true;
        else if ((idx >> 8) == binC) lst = true;
      }
    }
    const unsigned long long mt = __ballot(take);
    if (mt) {
      const int leader = __builtin_ctzll(mt);
      unsigned base = 0;
      if (lane == leader) base = atomicAdd(&s_pos, (unsigned)__builtin_popcountll(mt));
      base = (unsigned)__shfl((int)base, leader, 64);
      if (take) {
        const int rk = __builtin_popcountll(mt & ((1ull << lane) - 1ull));
        const unsigned p = base + (unsigned)rk;
        if (p < (unsigned)KPAD) sel[b * KPAD + p] = rec;
      }
    }
    if (lst) {
      const unsigned p = atomicAdd(&s_lcnt, 1u);
      if (p < 256u) s_lidx[p] = (unsigned)rec;
    }
  }
  __syncthreads();
  const unsigned lcnt = (s_lcnt < 256u) ? s_lcnt : 256u;  // bin C holds <=256 distinct indices
  const unsigned long long thrHi = ((unsigned long long)((ctrl[b].t1 << 20) | key20)) << 32;
  if (tid < (int)lcnt) {
    const unsigned my = s_lidx[tid];
    unsigned rk = 0;
    for (unsigned f = 0; f < lcnt; ++f) rk += (s_lidx[f] < my) ? 1u : 0u;
    if (rk < remC) {
      const unsigned p = atomicAdd(&s_pos, 1u);
      if (p < (unsigned)KPAD) sel[b * KPAD + p] = thrHi | (unsigned long long)my;
    }
  }
  __syncthreads();
  if (tid == 0) ctrl[b].total = s_pos;
}

// Pairwise rank + fused decode. key = (scorebits<<32) | ~idx; rank = #{keys > mine}.
__global__ __launch_bounds__(256) void rank_kernel(const Ctrl* __restrict__ ctrl,
                                                   const unsigned long long* __restrict__ sel,
                                                   const float* __restrict__ anchors,
                                                   const float* __restrict__ bbox,
                                                   float4* __restrict__ boxes, int N) {
  const int b = blockIdx.x & 7;
  const int it = blockIdx.x >> 3;    // 0..93
  const int tid = threadIdx.x;
  const int wv = tid >> 6, lane = tid & 63;
  __shared__ unsigned long long skey[KPAD];   // 48128 B
  __shared__ unsigned scnt[4][64];
  int total = (int)ctrl[b].total; if (total > KSEL) total = KSEL;
  for (int i = tid; i < KPAD; i += 256) {
    unsigned long long kp = 0ull;
    if (i < total) {
      const unsigned long long e = sel[b * KPAD + i];
      kp = (e & 0xFFFFFFFF00000000ull) | (unsigned long long)(0xFFFFFFFFu - (unsigned)e);
    }
    skey[i] = kp;
  }
  __syncthreads();
  const int me = it * 64 + lane;
  const unsigned long long myk = skey[me];
  const int chunk = KPAD / 4;
  const int lo = wv * chunk;
  unsigned cnt = 0;
#pragma unroll 8
  for (int c = 0; c < chunk; ++c) cnt += (skey[lo + c] > myk) ? 1u : 0u;
  scnt[wv][lane] = cnt;
  __syncthreads();
  if (wv == 0 && me < total) {
    const unsigned rank = scnt[0][lane] + scnt[1][lane] + scnt[2][lane] + scnt[3][lane];
    unsigned idx = 0xFFFFFFFFu - (unsigned)myk;
    if (idx >= (unsigned)N) idx = 0;
    const float4 A = ((const float4*)anchors)[(size_t)b * N + idx];
    const float4 R = ((const float4*)bbox)[(size_t)b * N + idx];
    const float d0 = R.x * 0.1f, d1 = R.y * 0.1f, d2 = R.z * 0.2f, d3 = R.w * 0.2f;
    const float h = A.z - A.x;
    const float w = A.w - A.y;
    const float cy = A.x + 0.5f * h + d0 * h;
    const float cx = A.y + 0.5f * w + d1 * w;
    const float e2 = (float)exp((double)d2);  // correctly-rounded f32 exp
    const float e3 = (float)exp((double)d3);
    const float h2 = h * e2;
    const float w2 = w * e3;
    float y1 = cy - 0.5f * h2;
    float x1 = cx - 0.5f * w2;
    float y2 = y1 + h2;
    float x2 = x1 + w2;
    y1 = fminf(fmaxf(y1, 0.0f), 1.0f);
    x1 = fminf(fmaxf(x1, 0.0f), 1.0f);
    y2 = fminf(fmaxf(y2, 0.0f), 1.0f);
    x2 = fminf(fmaxf(x2, 0.0f), 1.0f);
    boxes[b * KPAD + rank] = make_float4(y1, x1, y2, x2);
  }
}

// ---- 2048x2048 upper-triangular suppression matrix, row-major (unchanged, verified) ----
__global__ __launch_bounds__(256) void suppmat_kernel(const float4* __restrict__ boxes,
                                                      unsigned long long* __restrict__ mat) {
  const int b = blockIdx.x & 7;
  const int it = blockIdx.x >> 3;       // row tile 0..RTILES-1
  const int wv = threadIdx.x >> 6;
  const int lane = threadIdx.x & 63;
  const float4* gbox = boxes + b * KPAD;
  __shared__ float4 srow[64];
  __shared__ float sarea[64];
  __shared__ unsigned long long wbuf[64][SWORDS];   // 16 KiB
  if (threadIdx.x < 64) {
    const float4 v = gbox[it * 64 + threadIdx.x];
    srow[threadIdx.x] = v;
    sarea[threadIdx.x] = (v.z - v.x) * (v.w - v.y);
  }
  __syncthreads();
  float4 rb[16]; float rba[16];
#pragma unroll
  for (int k = 0; k < 16; ++k) { rb[k] = srow[wv * 16 + k]; rba[k] = sarea[wv * 16 + k]; }
  const double M = 0.7000000178813934326171875;
  for (int jt = it; jt < SWORDS; ++jt) {
    const int c = jt * 64 + lane;
    const float4 cv = gbox[c];
    const float ca = (cv.z - cv.x) * (cv.w - cv.y);
#pragma unroll
    for (int k = 0; k < 16; ++k) {
      const int i = it * 64 + wv * 16 + k;
      const float4 hb = rb[k];
      const float ha = rba[k];
      const float iy1 = fmaxf(hb.x, cv.x);
      const float ix1 = fmaxf(hb.y, cv.y);
      const float iy2 = fminf(hb.z, cv.z);
      const float ix2 = fminf(hb.w, cv.w);
      const float dy = fmaxf(iy2 - iy1, 0.0f);
      const float dx = fmaxf(ix2 - ix1, 0.0f);
      const float inter = dy * dx;
      const float denom = ha + ca - inter + 1e-12f;
      const bool s = (c > i) && ((double)inter >= M * (double)denom);
      const unsigned long long w = __ballot(s);
      if (lane == 0) wbuf[wv * 16 + k][jt] = w;
    }
  }
  __syncthreads();
  const int nw = SWORDS - it;
  unsigned long long* obase = mat + ((size_t)b * RMAX + (size_t)it * 64) * SWORDS;
  for (int q = threadIdx.x; q < 64 * nw; q += 256) {
    const int r = q / nw;
    const int k = q - r * nw;
    obase[(size_t)r * SWORDS + it + k] = wbuf[r][it + k];
  }
}

// Chunked exact greedy NMS with SPARSE replay (unchanged, verified round 11).
__global__ __launch_bounds__(64) void nmsscan_kernel(const Ctrl* __restrict__ ctrl,
                                                     const float4* __restrict__ boxes,
                                                     const unsigned long long* __restrict__ mat,
                                                     float* __restrict__ out) {
  const int b = blockIdx.x;
  const int lane = threadIdx.x;
  int total = (int)ctrl[b].total; if (total > KSEL) total = KSEL;
  const unsigned long long* rmat = mat + (size_t)b * RMAX * SWORDS;  // [row][w]
  const float4* gbox = boxes + b * KPAD;
  float4* outv = (float4*)(out + (size_t)b * PROP * 4);
  __shared__ int s_sel[PROP];
  __shared__ float4 s_hbox[PROP];
  const int lim = (total < RMAX) ? total : RMAX;
  const int nchunks = (lim + 63) >> 6;
  const bool wlane = lane < SWORDS;
  unsigned long long r0 = 0ull;     // removed word `lane` (lanes 0..SWORDS-1)
  int nsel = 0;

  unsigned long long diagN = (lane < lim) ? rmat[(size_t)lane * SWORDS] : 0ull;
  for (int c = 0; c < nchunks && nsel < PROP; ++c) {
    const int base = c << 6;
    const int n = ((lim - base) < 64) ? (lim - base) : 64;
    const unsigned long long diag = diagN;
    const int nb2 = base + 64;
    diagN = ((c + 1) < nchunks && (nb2 + lane) < lim)
              ? rmat[(size_t)(nb2 + lane) * SWORDS + (c + 1)] : 0ull;
    unsigned long long aw = ~__shfl(r0, c, 64);
    if (n < 64) aw &= ((1ull << n) - 1ull);
    unsigned long long S = __ballot(diag != 0ull);
    while (S) {
      const int s = __builtin_ctzll(S);
      S &= S - 1ull;
      const unsigned long long cm = __shfl(diag, s, 64);
      if ((aw >> s) & 1ull) aw &= ~cm;
    }
    unsigned long long acc = aw;
    const int need = PROP - nsel;
    int na = __popcll(acc);
    if (na > need) {
      unsigned long long t2 = acc, a2 = 0ull;
      for (int c2 = 0; c2 < need; ++c2) { a2 |= t2 & (0ull - t2); t2 &= t2 - 1ull; }
      acc = a2; na = need;
    }
    if ((acc >> lane) & 1ull) {
      const int r = __popcll(acc & ((1ull << lane) - 1ull));
      s_sel[nsel + r] = base + lane;
    }
    nsel += na;
    if (nsel >= PROP || c + 1 >= nchunks) continue;
    if (wlane) {
      const unsigned long long* rowbase = rmat + (size_t)base * SWORDS + lane;
      unsigned long long o = 0ull;
#pragma unroll
      for (int r = 0; r < 64; ++r) {
        const unsigned long long v = rowbase[(size_t)r * SWORDS];
        o |= (((acc >> r) & 1ull) ? v : 0ull);
      }
      r0 |= o;
    }
  }
  if (nsel < PROP && total > lim) {
    for (int k = lane; k < nsel; k += 64) s_hbox[k] = gbox[s_sel[k]];
    __syncthreads();
    const double M = 0.7000000178813934326171875;
    for (int i2 = lim; i2 < total && nsel < PROP; ++i2) {
      const float4 v = gbox[i2];
      const float a = (v.z - v.x) * (v.w - v.y);
      bool supp = false;
      for (int h = lane; h < nsel; h += 64) {
        const float4 hb = s_hbox[h];
        const float ha = (hb.z - hb.x) * (hb.w - hb.y);
        const float iy1 = fmaxf(hb.x, v.x);
        const float ix1 = fmaxf(hb.y, v.y);
        const float iy2 = fminf(hb.z, v.z);
        const float ix2 = fminf(hb.w, v.w);
        const float dy = fmaxf(iy2 - iy1, 0.0f);
        const float dx = fmaxf(ix2 - ix1, 0.0f);
        const float inter = dy * dx;
        const float denom = ha + a - inter + 1e-12f;
        if ((double)inter >= M * (double)denom) { supp = true; break; }
      }
      if (!__any(supp)) {
        if (lane == 0) { s_sel[nsel] = i2; s_hbox[nsel] = v; }
        ++nsel;
      }
    }
  }
  __syncthreads();
  for (int k = lane; k < PROP; k += 64)
    outv[k] = (k < nsel) ? gbox[s_sel[k]] : make_float4(0.f, 0.f, 0.f, 0.f);
}

// ---- fallback windowed NMS (boxes-only) for small ws ----
__global__ __launch_bounds__(1024) void nms_kernel(const float4* __restrict__ boxes, float* __restrict__ out) {
  const int b = blockIdx.x;
  const int tid = threadIdx.x;
  const int lane = tid & 63;
  const float4* gbox = boxes + b * KPAD;
  float* outB = out + b * (PROP * 4);
  __shared__ unsigned long long smask[94];
  __shared__ int s_widx[64];
  __shared__ float4 s_wbox[64];
  __shared__ float s_wha[64];
  __shared__ int s_cnt, s_nAcc, s_total, s_cursor;
  for (int k = tid; k < 94; k += 1024)
    smask[k] = (k == 93) ? ((1ull << 48) - 1ull) : ~0ull;
  if (tid == 0) { s_cursor = 0; s_total = 0; }
  __syncthreads();
  const double M = 0.7000000178813934326171875;
  for (int round = 0; round < PROP; ++round) {
    if (tid == 0) {
      int cnt = 0;
      const int cur = s_cursor;
      int w = cur >> 6;
      unsigned long long word = (w < 94) ? (smask[w] & (~0ull << (cur & 63))) : 0ull;
      while (cnt < 64) {
        while (word == 0ull && ++w < 94) word = smask[w];
        if (w >= 94) break;
        const int bit = __builtin_ctzll(word);
        word &= word - 1ull;
        s_widx[cnt++] = (w << 6) | bit;
      }
      s_cnt = cnt;
      s_cursor = cnt ? (s_widx[cnt - 1] + 1) : KSEL;
    }
    __syncthreads();
    const int cnt = s_cnt;
    const int tailStart = s_cursor;
    if (cnt == 0) break;
    if (tid < 64) {
      const int j = (lane < cnt) ? s_widx[lane] : -1;
      float4 v = make_float4(0.f, 0.f, 0.f, 0.f);
      if (j >= 0) v = gbox[j];
      const float a = (v.z - v.x) * (v.w - v.y);
      const int totalOld = s_total;
      unsigned long long aliveW = __ballot(j >= 0);
      unsigned long long acc = 0ull;
      for (int i = 0; i < 64; ++i) {
        const float hx = __shfl(v.x, i), hy = __shfl(v.y, i);
        const float hz = __shfl(v.z, i), hw = __shfl(v.w, i);
        const float ha = __shfl(a, i);
        bool s = false;
        if (j >= 0 && lane > i) {
          const float iy1 = fmaxf(hx, v.x);
          const float ix1 = fmaxf(hy, v.y);
          const float iy2 = fminf(hz, v.z);
          const float ix2 = fminf(hw, v.w);
          const float dy = fmaxf(iy2 - iy1, 0.0f);
          const float dx = fmaxf(ix2 - ix1, 0.0f);
          const float inter = dy * dx;
          const float denom = ha + a - inter + 1e-12f;
          s = ((double)inter >= M * (double)denom);
        }
        const unsigned long long m = __ballot(s);
        if (aliveW & (1ull << i)) { acc |= 1ull << i; aliveW &= ~m; }
      }
      const int need = PROP - totalOld;
      int na = __popcll(acc);
      if (na > need) {
        unsigned long long t = acc, a2 = 0ull;
        for (int c2 = 0; c2 < need; ++c2) { a2 |= t & (0ull - t); t &= t - 1ull; }
        acc = a2; na = need;
      }
      if ((acc >> lane) & 1ull) {
        const int r = __popcll(acc & ((1ull << lane) - 1ull));
        float* o = outB + (size_t)(totalOld + r) * 4;
        o[0] = v.x; o[1] = v.y; o[2] = v.z; o[3] = v.w;
        s_wbox[r] = v; s_wha[r] = a;
      }
      if (lane == 0) { s_nAcc = na; s_total = totalOld + na; }
      if (j >= 0) atomicAnd(&smask[j >> 6], ~(1ull << (j & 63)));
    }
    __syncthreads();
    const int total = s_total;
    const int nAcc = s_nAcc;
    if (total >= PROP) break;
    for (int j = tailStart + tid; j < KSEL; j += 1024) {
      if (!((smask[j >> 6] >> (j & 63)) & 1ull)) continue;
      const float4 v = gbox[j];
      const float a = (v.z - v.x) * (v.w - v.y);
      bool supp = false;
      for (int r = 0; r < nAcc; ++r) {
        const float4 hb = s_wbox[r];
        const float ha = s_wha[r];
        const float iy1 = fmaxf(hb.x, v.x);
        const float ix1 = fmaxf(hb.y, v.y);
        const float iy2 = fminf(hb.z, v.z);
        const float ix2 = fminf(hb.w, v.w);
        const float dy = fmaxf(iy2 - iy1, 0.0f);
        const float dx = fmaxf(ix2 - ix1, 0.0f);
        const float inter = dy * dx;
        const float denom = ha + a - inter + 1e-12f;
        if ((double)inter >= M * (double)denom) { supp = true; break; }
      }
      if (supp) atomicAnd(&smask[j >> 6], ~(1ull << (j & 63)));
    }
    __syncthreads();
  }
  const int written = s_total;
  for (int u = written * 4 + tid; u < PROP * 4; u += 1024) outB[u] = 0.0f;
}

extern "C" void kernel_launch(void* const* d_in, const int* in_sizes, int n_in,
                              void* d_out, int out_size, void* d_ws, size_t ws_size,
                              hipStream_t stream) {
  (void)n_in; (void)out_size;
  const float* probs = (const float*)d_in[0];
  const float* bbox = (const float*)d_in[1];
  const float* anchors = (const float*)d_in[2];
  float* out = (float*)d_out;
  char* ws = (char*)d_ws;
  const int N = in_sizes[0] / (NB * 2);  // 261888

  unsigned* hist1 = (unsigned*)(ws + OFF_HIST1);
  Ctrl* ctrl = (Ctrl*)(ws + OFF_CTRL);
  unsigned long long* sel = (unsigned long long*)(ws + OFF_SEL);
  unsigned long long* eq2 = (unsigned long long*)(ws + OFF_EQ2);
  float4* boxes = (float4*)(ws + OFF_BOX);
  unsigned long long* mat = (unsigned long long*)(ws + OFF_MAT);

  const int zeroN = (int)((OFF_SEL - OFF_HIST1) / 4);  // hist1 + ctrl
  zero_kernel<<<dim3((zeroN + 255) / 256), dim3(256), 0, stream>>>((unsigned*)ws, zeroN);

  const int gx = (N + 2047) / 2048;      // 128
  hist12_kernel<<<dim3(gx, NB), dim3(256), 0, stream>>>(probs, hist1, N);
  scan12_kernel<<<dim3(NB), dim3(64), 0, stream>>>(hist1, ctrl);
  compact2_kernel<<<dim3(gx, NB), dim3(256), 0, stream>>>(probs, ctrl, sel, eq2, N);
  eqres2_kernel<<<dim3(NB), dim3(256), 0, stream>>>(ctrl, eq2, sel);
  rank_kernel<<<dim3(NTILE * NB), dim3(256), 0, stream>>>(ctrl, sel, anchors, bbox, boxes, N);

  if (ws_size >= (size_t)OFF_MAT + MAT_BYTES) {
    suppmat_kernel<<<dim3(RTILES * NB), dim3(256), 0, stream>>>(boxes, mat);
    nmsscan_kernel<<<dim3(NB), dim3(64), 0, stream>>>(ctrl, boxes, mat, out);
  } else {
    nms_kernel<<<dim3(NB), dim3(1024), 0, stream>>>(boxes, out);
  }
}

// Round 14
// 138.586 us; speedup vs baseline: 1.7290x; 1.2841x over previous
//
#include <hip/hip_runtime.h>

#pragma clang fp contract(off)

#define NB 8
#define KSEL 6000
#define KPAD 6016
#define PROP 1000
#define NTILE 94
#define RMAX 2048
#define RTILES 32
#define SWORDS 32
#define EQ2CAP 262144

// ws layout (bytes)
#define OFF_HIST1 0u          // 8*4096*4 = 131072
#define OFF_CTRL  131072u     // 512 -> 131584
#define OFF_SEL   131584u     // 8*6016*8 = 385024 -> 516608
#define OFF_EQ2   516608u     // 8*262144*8 = 16777216 -> 17293824
#define OFF_BOX   17293824u   // 8*6016*16 = 770048 -> 18063872
#define OFF_MAT   18063872u   // 8*2048*32*8 = 4194304 -> 22258176
#define MAT_BYTES 4194304ull

struct Ctrl {
  unsigned t1, rem1, selCount, eqCount, total;
  unsigned pad[11];
};

__global__ __launch_bounds__(256) void zero_kernel(unsigned* p, int n) {
  int i = blockIdx.x * 256 + threadIdx.x;
  if (i < n) p[i] = 0u;
}

// Pass 1: 4096-bin histogram of top-12 bits of fg scores; float4 loads (2 elems each).
__global__ __launch_bounds__(256) void hist12_kernel(const float* __restrict__ probs,
                                                     unsigned* __restrict__ hist, int N) {
  __shared__ unsigned lh[4096];
  const int b = blockIdx.y;
  for (int k = threadIdx.x; k < 4096; k += 256) lh[k] = 0u;
  __syncthreads();
  const int start = blockIdx.x * 2048;
  const int end = min(start + 2048, N);
#pragma unroll
  for (int j = 0; j < 4; ++j) {
    const int i = start + j * 512 + (int)threadIdx.x * 2;
    if (i < end) {
      const float4 p2 = *(const float4*)(probs + ((size_t)b * N + i) * 2);
      atomicAdd(&lh[__float_as_uint(p2.y) >> 20], 1u);
      if (i + 1 < end) atomicAdd(&lh[__float_as_uint(p2.w) >> 20], 1u);
    }
  }
  __syncthreads();
  for (int k = threadIdx.x; k < 4096; k += 256) {
    const unsigned v = lh[k];
    if (v) atomicAdd(&hist[b * 4096 + k], v);
  }
}

// one wave per image: descending cumulative scan over 4096 bins -> t1, rem1
__global__ __launch_bounds__(64) void scan12_kernel(const unsigned* __restrict__ hist,
                                                    Ctrl* __restrict__ ctrl) {
  const int b = blockIdx.x;
  const int lane = threadIdx.x;
  const unsigned target = (unsigned)KSEL;
  const unsigned* h = hist + b * 4096;
  const int topbin = 4095 - lane * 64;
  unsigned mysum = 0;
  for (int c = 0; c < 64; c++) mysum += h[topbin - c];
  unsigned cum = mysum;
  for (int off = 1; off < 64; off <<= 1) {
    const unsigned v = __shfl_up(cum, off, 64);
    if (lane >= off) cum += v;
  }
  const unsigned prev = cum - mysum;
  if (prev < target && cum >= target) {
    unsigned c2 = prev;
    for (int c = 0; c < 64; c++) {
      const int bin = topbin - c;
      const unsigned hv = h[bin];
      if (c2 + hv >= target) { ctrl[b].t1 = (unsigned)bin; ctrl[b].rem1 = target - c2; break; }
      c2 += hv;
    }
  }
}

// Pass 2: block-aggregated compaction (verified round 13).
__global__ __launch_bounds__(256) void compact2_kernel(const float* __restrict__ probs,
                                                       Ctrl* __restrict__ ctrl,
                                                       unsigned long long* __restrict__ sel,
                                                       unsigned long long* __restrict__ eq2, int N) {
  __shared__ unsigned long long buf[2048];   // 16 KiB
  __shared__ unsigned s_ngt, s_neq, s_gbase, s_ebase;
  const int b = blockIdx.y;
  const int tid = threadIdx.x;
  const unsigned t1 = ctrl[b].t1;
  const int start = blockIdx.x * 2048;
  const int end = min(start + 2048, N);
  if (tid == 0) { s_ngt = 0u; s_neq = 0u; }
  __syncthreads();
  unsigned bits[8];
  int idxs[8];
#pragma unroll
  for (int j = 0; j < 4; ++j) {
    const int i = start + j * 512 + tid * 2;
    float4 p2 = make_float4(0.f, 0.f, 0.f, 0.f);
    if (i < end) p2 = *(const float4*)(probs + ((size_t)b * N + i) * 2);
    bits[j * 2]     = (i < end) ? __float_as_uint(p2.y) : 0u;
    idxs[j * 2]     = (i < end) ? i : -1;
    bits[j * 2 + 1] = (i + 1 < end) ? __float_as_uint(p2.w) : 0u;
    idxs[j * 2 + 1] = (i + 1 < end) ? (i + 1) : -1;
  }
#pragma unroll
  for (int e = 0; e < 8; ++e) {
    if (idxs[e] >= 0) {
      const unsigned top = bits[e] >> 20;
      if (top > t1) {
        const unsigned p = atomicAdd(&s_ngt, 1u);
        buf[p] = ((unsigned long long)bits[e] << 32) | (unsigned)idxs[e];
      } else if (top == t1) {
        const unsigned p = atomicAdd(&s_neq, 1u);
        buf[2047 - p] = ((unsigned long long)bits[e] << 32) | (unsigned)idxs[e];
      }
    }
  }
  __syncthreads();
  const unsigned ngt = s_ngt, neq = s_neq;
  if (tid == 0 && ngt) s_gbase = atomicAdd(&ctrl[b].selCount, ngt);
  if (tid == 1 && neq) s_ebase = atomicAdd(&ctrl[b].eqCount, neq);
  __syncthreads();
  for (unsigned k = tid; k < ngt; k += 256) {
    const unsigned p = s_gbase + k;
    if (p < (unsigned)KPAD) sel[b * KPAD + p] = buf[k];
  }
  for (unsigned k = tid; k < neq; k += 256) {
    const unsigned p = s_ebase + k;
    if (p < (unsigned)EQ2CAP) eq2[(size_t)b * EQ2CAP + p] = buf[2047 - k];
  }
}

// wave-0 scans over a 1024-bin LDS histogram
__device__ inline void scan1024_desc(const unsigned* h, unsigned target, int lane,
                                     unsigned* outBin, unsigned* outRem) {
  const int topbin = 1023 - lane * 16;
  unsigned mysum = 0;
  for (int c = 0; c < 16; ++c) mysum += h[topbin - c];
  unsigned cum = mysum;
  for (int off = 1; off < 64; off <<= 1) {
    const unsigned v = __shfl_up(cum, off, 64);
    if (lane >= off) cum += v;
  }
  const unsigned prev = cum - mysum;
  if (prev < target && cum >= target) {
    unsigned c2 = prev;
    for (int c = 0; c < 16; ++c) {
      const int bin = topbin - c;
      const unsigned hv = h[bin];
      if (c2 + hv >= target) { *outBin = (unsigned)bin; *outRem = target - c2; break; }
      c2 += hv;
    }
  }
}
__device__ inline void scan1024_asc(const unsigned* h, unsigned target, int lane,
                                    unsigned* outBin, unsigned* outRem) {
  const int botbin = lane * 16;
  unsigned mysum = 0;
  for (int c = 0; c < 16; ++c) mysum += h[botbin + c];
  unsigned cum = mysum;
  for (int off = 1; off < 64; off <<= 1) {
    const unsigned v = __shfl_up(cum, off, 64);
    if (lane >= off) cum += v;
  }
  const unsigned prev = cum - mysum;
  if (prev < target && cum >= target) {
    unsigned c2 = prev;
    for (int c = 0; c < 16; ++c) {
      const int bin = botbin + c;
      const unsigned hv = h[bin];
      if (c2 + hv >= target) { *outBin = (unsigned)bin; *outRem = target - c2; break; }
      c2 += hv;
    }
  }
}

// Tie resolution within the t1 bin (verified round 12/13).
__global__ __launch_bounds__(256) void eqres2_kernel(Ctrl* __restrict__ ctrl,
                                                     const unsigned long long* __restrict__ eq2,
                                                     unsigned long long* __restrict__ sel) {
  __shared__ unsigned h1[1024];
  __shared__ unsigned s_binA, s_remA, s_binB, s_remB, s_binC, s_remC;
  __shared__ unsigned s_pos, s_lcnt;
  __shared__ unsigned s_lidx[256];
  const int b = blockIdx.x;
  const int tid = threadIdx.x, lane = tid & 63, wv = tid >> 6;
  unsigned cnt = ctrl[b].eqCount; if (cnt > (unsigned)EQ2CAP) cnt = EQ2CAP;
  const unsigned rem1 = ctrl[b].rem1;
  const unsigned long long* E = eq2 + (size_t)b * EQ2CAP;

  for (int k = tid; k < 1024; k += 256) h1[k] = 0u;
  __syncthreads();
  for (unsigned k = tid; k < cnt; k += 256)
    atomicAdd(&h1[((unsigned)(E[k] >> 32) >> 10) & 1023u], 1u);
  __syncthreads();
  if (wv == 0) scan1024_desc(h1, rem1, lane, &s_binA, &s_remA);
  __syncthreads();
  const unsigned binA = s_binA, remA = s_remA;
  __syncthreads();
  for (int k = tid; k < 1024; k += 256) h1[k] = 0u;
  __syncthreads();
  for (unsigned k = tid; k < cnt; k += 256) {
    const unsigned bits = (unsigned)(E[k] >> 32);
    if (((bits >> 10) & 1023u) == binA) atomicAdd(&h1[bits & 1023u], 1u);
  }
  __syncthreads();
  if (wv == 0) scan1024_desc(h1, remA, lane, &s_binB, &s_remB);
  __syncthreads();
  const unsigned binB = s_binB, remB = s_remB;
  const unsigned key20 = (binA << 10) | binB;
  __syncthreads();
  for (int k = tid; k < 1024; k += 256) h1[k] = 0u;
  __syncthreads();
  for (unsigned k = tid; k < cnt; k += 256) {
    const unsigned long long r = E[k];
    if (((unsigned)(r >> 32) & 0xFFFFFu) == key20) atomicAdd(&h1[((unsigned)r) >> 8], 1u);
  }
  __syncthreads();
  if (wv == 0) scan1024_asc(h1, remB, lane, &s_binC, &s_remC);
  if (tid == 0) { s_pos = ctrl[b].selCount; s_lcnt = 0u; }
  __syncthreads();
  const unsigned binC = s_binC, remC = s_remC;
  for (unsigned k0 = 0; k0 < cnt; k0 += 256) {
    const unsigned k = k0 + tid;
    bool take = false, lst = false;
    unsigned long long rec = 0ull;
    if (k < cnt) {
      rec = E[k];
      const unsigned bits = (unsigned)(rec >> 32);
      const unsigned k20 = bits & 0xFFFFFu;
      const unsigned idx = (unsigned)rec;
      if ((k20 >> 10) > binA) take = true;
      else if ((k20 >> 10) == binA && (k20 & 1023u) > binB) take = true;
      else if (k20 == key20) {
        if ((idx >> 8) < binC) take = true;
        else if ((idx >> 8) == binC) lst = true;
      }
    }
    const unsigned long long mt = __ballot(take);
    if (mt) {
      const int leader = __builtin_ctzll(mt);
      unsigned base = 0;
      if (lane == leader) base = atomicAdd(&s_pos, (unsigned)__builtin_popcountll(mt));
      base = (unsigned)__shfl((int)base, leader, 64);
      if (take) {
        const int rk = __builtin_popcountll(mt & ((1ull << lane) - 1ull));
        const unsigned p = base + (unsigned)rk;
        if (p < (unsigned)KPAD) sel[b * KPAD + p] = rec;
      }
    }
    if (lst) {
      const unsigned p = atomicAdd(&s_lcnt, 1u);
      if (p < 256u) s_lidx[p] = (unsigned)rec;
    }
  }
  __syncthreads();
  const unsigned lcnt = (s_lcnt < 256u) ? s_lcnt : 256u;
  const unsigned long long thrHi = ((unsigned long long)((ctrl[b].t1 << 20) | key20)) << 32;
  if (tid < (int)lcnt) {
    const unsigned my = s_lidx[tid];
    unsigned rk = 0;
    for (unsigned f = 0; f < lcnt; ++f) rk += (s_lidx[f] < my) ? 1u : 0u;
    if (rk < remC) {
      const unsigned p = atomicAdd(&s_pos, 1u);
      if (p < (unsigned)KPAD) sel[b * KPAD + p] = thrHi | (unsigned long long)my;
    }
  }
  __syncthreads();
  if (tid == 0) ctrl[b].total = s_pos;
}

// Pairwise rank + fused decode (verified).
__global__ __launch_bounds__(256) void rank_kernel(const Ctrl* __restrict__ ctrl,
                                                   const unsigned long long* __restrict__ sel,
                                                   const float* __restrict__ anchors,
                                                   const float* __restrict__ bbox,
                                                   float4* __restrict__ boxes, int N) {
  const int b = blockIdx.x & 7;
  const int it = blockIdx.x >> 3;    // 0..93
  const int tid = threadIdx.x;
  const int wv = tid >> 6, lane = tid & 63;
  __shared__ unsigned long long skey[KPAD];   // 48128 B
  __shared__ unsigned scnt[4][64];
  int total = (int)ctrl[b].total; if (total > KSEL) total = KSEL;
  for (int i = tid; i < KPAD; i += 256) {
    unsigned long long kp = 0ull;
    if (i < total) {
      const unsigned long long e = sel[b * KPAD + i];
      kp = (e & 0xFFFFFFFF00000000ull) | (unsigned long long)(0xFFFFFFFFu - (unsigned)e);
    }
    skey[i] = kp;
  }
  __syncthreads();
  const int me = it * 64 + lane;
  const unsigned long long myk = skey[me];
  const int chunk = KPAD / 4;
  const int lo = wv * chunk;
  unsigned cnt = 0;
#pragma unroll 8
  for (int c = 0; c < chunk; ++c) cnt += (skey[lo + c] > myk) ? 1u : 0u;
  scnt[wv][lane] = cnt;
  __syncthreads();
  if (wv == 0 && me < total) {
    const unsigned rank = scnt[0][lane] + scnt[1][lane] + scnt[2][lane] + scnt[3][lane];
    unsigned idx = 0xFFFFFFFFu - (unsigned)myk;
    if (idx >= (unsigned)N) idx = 0;
    const float4 A = ((const float4*)anchors)[(size_t)b * N + idx];
    const float4 R = ((const float4*)bbox)[(size_t)b * N + idx];
    const float d0 = R.x * 0.1f, d1 = R.y * 0.1f, d2 = R.z * 0.2f, d3 = R.w * 0.2f;
    const float h = A.z - A.x;
    const float w = A.w - A.y;
    const float cy = A.x + 0.5f * h + d0 * h;
    const float cx = A.y + 0.5f * w + d1 * w;
    const float e2 = (float)exp((double)d2);  // correctly-rounded f32 exp
    const float e3 = (float)exp((double)d3);
    const float h2 = h * e2;
    const float w2 = w * e3;
    float y1 = cy - 0.5f * h2;
    float x1 = cx - 0.5f * w2;
    float y2 = y1 + h2;
    float x2 = x1 + w2;
    y1 = fminf(fmaxf(y1, 0.0f), 1.0f);
    x1 = fminf(fmaxf(x1, 0.0f), 1.0f);
    y2 = fminf(fmaxf(y2, 0.0f), 1.0f);
    x2 = fminf(fmaxf(x2, 0.0f), 1.0f);
    boxes[b * KPAD + rank] = make_float4(y1, x1, y2, x2);
  }
}

// ---- suppression matrix, pair-tile decomposition for load balance ----
// One block per (image, tile-pair it<=jt): 64 rows (LDS) x 64 cols (lanes), each wave
// computes 16 rows -> 16 IoU bodies per lane. Writes word jt of rows it*64..+63
// directly to the row-major matrix mat[row][SWORDS]. Same (c > i) masking; output
// bit-identical to the previous suppmat.
__global__ __launch_bounds__(256) void suppmat_kernel(const float4* __restrict__ boxes,
                                                      unsigned long long* __restrict__ mat) {
  const int b = blockIdx.x & 7;
  int t = blockIdx.x >> 3;
  int it = 0, rem = SWORDS;
  while (t >= rem) { t -= rem; ++it; rem = SWORDS - it; }
  const int jt = it + t;
  const int wv = threadIdx.x >> 6;
  const int lane = threadIdx.x & 63;
  const float4* gbox = boxes + b * KPAD;
  __shared__ float4 srow[64];
  __shared__ float sarea[64];
  if (threadIdx.x < 64) {
    const float4 v = gbox[it * 64 + threadIdx.x];
    srow[threadIdx.x] = v;
    sarea[threadIdx.x] = (v.z - v.x) * (v.w - v.y);
  }
  const int c = jt * 64 + lane;
  const float4 cv = gbox[c];
  const float ca = (cv.z - cv.x) * (cv.w - cv.y);
  __syncthreads();
  const double M = 0.7000000178813934326171875;
  unsigned long long* obase = mat + ((size_t)b * RMAX + (size_t)it * 64) * SWORDS + jt;
#pragma unroll
  for (int k = 0; k < 16; ++k) {
    const int r = wv * 16 + k;
    const int i = it * 64 + r;
    const float4 hb = srow[r];
    const float ha = sarea[r];
    const float iy1 = fmaxf(hb.x, cv.x);
    const float ix1 = fmaxf(hb.y, cv.y);
    const float iy2 = fminf(hb.z, cv.z);
    const float ix2 = fminf(hb.w, cv.w);
    const float dy = fmaxf(iy2 - iy1, 0.0f);
    const float dx = fmaxf(ix2 - ix1, 0.0f);
    const float inter = dy * dx;
    const float denom = ha + ca - inter + 1e-12f;
    const bool s = (c > i) && ((double)inter >= M * (double)denom);
    const unsigned long long w = __ballot(s);
    if (lane == 0) obase[(size_t)r * SWORDS] = w;
  }
}

// Chunked exact greedy NMS with SPARSE replay (unchanged, verified round 11).
__global__ __launch_bounds__(64) void nmsscan_kernel(const Ctrl* __restrict__ ctrl,
                                                     const float4* __restrict__ boxes,
                                                     const unsigned long long* __restrict__ mat,
                                                     float* __restrict__ out) {
  const int b = blockIdx.x;
  const int lane = threadIdx.x;
  int total = (int)ctrl[b].total; if (total > KSEL) total = KSEL;
  const unsigned long long* rmat = mat + (size_t)b * RMAX * SWORDS;  // [row][w]
  const float4* gbox = boxes + b * KPAD;
  float4* outv = (float4*)(out + (size_t)b * PROP * 4);
  __shared__ int s_sel[PROP];
  __shared__ float4 s_hbox[PROP];
  const int lim = (total < RMAX) ? total : RMAX;
  const int nchunks = (lim + 63) >> 6;
  const bool wlane = lane < SWORDS;
  unsigned long long r0 = 0ull;     // removed word `lane` (lanes 0..SWORDS-1)
  int nsel = 0;

  unsigned long long diagN = (lane < lim) ? rmat[(size_t)lane * SWORDS] : 0ull;
  for (int c = 0; c < nchunks && nsel < PROP; ++c) {
    const int base = c << 6;
    const int n = ((lim - base) < 64) ? (lim - base) : 64;
    const unsigned long long diag = diagN;
    const int nb2 = base + 64;
    diagN = ((c + 1) < nchunks && (nb2 + lane) < lim)
              ? rmat[(size_t)(nb2 + lane) * SWORDS + (c + 1)] : 0ull;
    unsigned long long aw = ~__shfl(r0, c, 64);
    if (n < 64) aw &= ((1ull << n) - 1ull);
    unsigned long long S = __ballot(diag != 0ull);
    while (S) {
      const int s = __builtin_ctzll(S);
      S &= S - 1ull;
      const unsigned long long cm = __shfl(diag, s, 64);
      if ((aw >> s) & 1ull) aw &= ~cm;
    }
    unsigned long long acc = aw;
    const int need = PROP - nsel;
    int na = __popcll(acc);
    if (na > need) {
      unsigned long long t2 = acc, a2 = 0ull;
      for (int c2 = 0; c2 < need; ++c2) { a2 |= t2 & (0ull - t2); t2 &= t2 - 1ull; }
      acc = a2; na = need;
    }
    if ((acc >> lane) & 1ull) {
      const int r = __popcll(acc & ((1ull << lane) - 1ull));
      s_sel[nsel + r] = base + lane;
    }
    nsel += na;
    if (nsel >= PROP || c + 1 >= nchunks) continue;
    if (wlane) {
      const unsigned long long* rowbase = rmat + (size_t)base * SWORDS + lane;
      unsigned long long o = 0ull;
#pragma unroll
      for (int r = 0; r < 64; ++r) {
        const unsigned long long v = rowbase[(size_t)r * SWORDS];
        o |= (((acc >> r) & 1ull) ? v : 0ull);
      }
      r0 |= o;
    }
  }
  if (nsel < PROP && total > lim) {
    for (int k = lane; k < nsel; k += 64) s_hbox[k] = gbox[s_sel[k]];
    __syncthreads();
    const double M = 0.7000000178813934326171875;
    for (int i2 = lim; i2 < total && nsel < PROP; ++i2) {
      const float4 v = gbox[i2];
      const float a = (v.z - v.x) * (v.w - v.y);
      bool supp = false;
      for (int h = lane; h < nsel; h += 64) {
        const float4 hb = s_hbox[h];
        const float ha = (hb.z - hb.x) * (hb.w - hb.y);
        const float iy1 = fmaxf(hb.x, v.x);
        const float ix1 = fmaxf(hb.y, v.y);
        const float iy2 = fminf(hb.z, v.z);
        const float ix2 = fminf(hb.w, v.w);
        const float dy = fmaxf(iy2 - iy1, 0.0f);
        const float dx = fmaxf(ix2 - ix1, 0.0f);
        const float inter = dy * dx;
        const float denom = ha + a - inter + 1e-12f;
        if ((double)inter >= M * (double)denom) { supp = true; break; }
      }
      if (!__any(supp)) {
        if (lane == 0) { s_sel[nsel] = i2; s_hbox[nsel] = v; }
        ++nsel;
      }
    }
  }
  __syncthreads();
  for (int k = lane; k < PROP; k += 64)
    outv[k] = (k < nsel) ? gbox[s_sel[k]] : make_float4(0.f, 0.f, 0.f, 0.f);
}

// ---- fallback windowed NMS (boxes-only) for small ws ----
__global__ __launch_bounds__(1024) void nms_kernel(const float4* __restrict__ boxes, float* __restrict__ out) {
  const int b = blockIdx.x;
  const int tid = threadIdx.x;
  const int lane = tid & 63;
  const float4* gbox = boxes + b * KPAD;
  float* outB = out + b * (PROP * 4);
  __shared__ unsigned long long smask[94];
  __shared__ int s_widx[64];
  __shared__ float4 s_wbox[64];
  __shared__ float s_wha[64];
  __shared__ int s_cnt, s_nAcc, s_total, s_cursor;
  for (int k = tid; k < 94; k += 1024)
    smask[k] = (k == 93) ? ((1ull << 48) - 1ull) : ~0ull;
  if (tid == 0) { s_cursor = 0; s_total = 0; }
  __syncthreads();
  const double M = 0.7000000178813934326171875;
  for (int round = 0; round < PROP; ++round) {
    if (tid == 0) {
      int cnt = 0;
      const int cur = s_cursor;
      int w = cur >> 6;
      unsigned long long word = (w < 94) ? (smask[w] & (~0ull << (cur & 63))) : 0ull;
      while (cnt < 64) {
        while (word == 0ull && ++w < 94) word = smask[w];
        if (w >= 94) break;
        const int bit = __builtin_ctzll(word);
        word &= word - 1ull;
        s_widx[cnt++] = (w << 6) | bit;
      }
      s_cnt = cnt;
      s_cursor = cnt ? (s_widx[cnt - 1] + 1) : KSEL;
    }
    __syncthreads();
    const int cnt = s_cnt;
    const int tailStart = s_cursor;
    if (cnt == 0) break;
    if (tid < 64) {
      const int j = (lane < cnt) ? s_widx[lane] : -1;
      float4 v = make_float4(0.f, 0.f, 0.f, 0.f);
      if (j >= 0) v = gbox[j];
      const float a = (v.z - v.x) * (v.w - v.y);
      const int totalOld = s_total;
      unsigned long long aliveW = __ballot(j >= 0);
      unsigned long long acc = 0ull;
      for (int i = 0; i < 64; ++i) {
        const float hx = __shfl(v.x, i), hy = __shfl(v.y, i);
        const float hz = __shfl(v.z, i), hw = __shfl(v.w, i);
        const float ha = __shfl(a, i);
        bool s = false;
        if (j >= 0 && lane > i) {
          const float iy1 = fmaxf(hx, v.x);
          const float ix1 = fmaxf(hy, v.y);
          const float iy2 = fminf(hz, v.z);
          const float ix2 = fminf(hw, v.w);
          const float dy = fmaxf(iy2 - iy1, 0.0f);
          const float dx = fmaxf(ix2 - ix1, 0.0f);
          const float inter = dy * dx;
          const float denom = ha + a - inter + 1e-12f;
          s = ((double)inter >= M * (double)denom);
        }
        const unsigned long long m = __ballot(s);
        if (aliveW & (1ull << i)) { acc |= 1ull << i; aliveW &= ~m; }
      }
      const int need = PROP - totalOld;
      int na = __popcll(acc);
      if (na > need) {
        unsigned long long t = acc, a2 = 0ull;
        for (int c2 = 0; c2 < need; ++c2) { a2 |= t & (0ull - t); t &= t - 1ull; }
        acc = a2; na = need;
      }
      if ((acc >> lane) & 1ull) {
        const int r = __popcll(acc & ((1ull << lane) - 1ull));
        float* o = outB + (size_t)(totalOld + r) * 4;
        o[0] = v.x; o[1] = v.y; o[2] = v.z; o[3] = v.w;
        s_wbox[r] = v; s_wha[r] = a;
      }
      if (lane == 0) { s_nAcc = na; s_total = totalOld + na; }
      if (j >= 0) atomicAnd(&smask[j >> 6], ~(1ull << (j & 63)));
    }
    __syncthreads();
    const int total = s_total;
    const int nAcc = s_nAcc;
    if (total >= PROP) break;
    for (int j = tailStart + tid; j < KSEL; j += 1024) {
      if (!((smask[j >> 6] >> (j & 63)) & 1ull)) continue;
      const float4 v = gbox[j];
      const float a = (v.z - v.x) * (v.w - v.y);
      bool supp = false;
      for (int r = 0; r < nAcc; ++r) {
        const float4 hb = s_wbox[r];
        const float ha = s_wha[r];
        const float iy1 = fmaxf(hb.x, v.x);
        const float ix1 = fmaxf(hb.y, v.y);
        const float iy2 = fminf(hb.z, v.z);
        const float ix2 = fminf(hb.w, v.w);
        const float dy = fmaxf(iy2 - iy1, 0.0f);
        const float dx = fmaxf(ix2 - ix1, 0.0f);
        const float inter = dy * dx;
        const float denom = ha + a - inter + 1e-12f;
        if ((double)inter >= M * (double)denom) { supp = true; break; }
      }
      if (supp) atomicAnd(&smask[j >> 6], ~(1ull << (j & 63)));
    }
    __syncthreads();
  }
  const int written = s_total;
  for (int u = written * 4 + tid; u < PROP * 4; u += 1024) outB[u] = 0.0f;
}

extern "C" void kernel_launch(void* const* d_in, const int* in_sizes, int n_in,
                              void* d_out, int out_size, void* d_ws, size_t ws_size,
                              hipStream_t stream) {
  (void)n_in; (void)out_size;
  const float* probs = (const float*)d_in[0];
  const float* bbox = (const float*)d_in[1];
  const float* anchors = (const float*)d_in[2];
  float* out = (float*)d_out;
  char* ws = (char*)d_ws;
  const int N = in_sizes[0] / (NB * 2);  // 261888

  unsigned* hist1 = (unsigned*)(ws + OFF_HIST1);
  Ctrl* ctrl = (Ctrl*)(ws + OFF_CTRL);
  unsigned long long* sel = (unsigned long long*)(ws + OFF_SEL);
  unsigned long long* eq2 = (unsigned long long*)(ws + OFF_EQ2);
  float4* boxes = (float4*)(ws + OFF_BOX);
  unsigned long long* mat = (unsigned long long*)(ws + OFF_MAT);

  const int zeroN = (int)((OFF_SEL - OFF_HIST1) / 4);  // hist1 + ctrl
  zero_kernel<<<dim3((zeroN + 255) / 256), dim3(256), 0, stream>>>((unsigned*)ws, zeroN);

  const int gx = (N + 2047) / 2048;      // 128
  hist12_kernel<<<dim3(gx, NB), dim3(256), 0, stream>>>(probs, hist1, N);
  scan12_kernel<<<dim3(NB), dim3(64), 0, stream>>>(hist1, ctrl);
  compact2_kernel<<<dim3(gx, NB), dim3(256), 0, stream>>>(probs, ctrl, sel, eq2, N);
  eqres2_kernel<<<dim3(NB), dim3(256), 0, stream>>>(ctrl, eq2, sel);
  rank_kernel<<<dim3(NTILE * NB), dim3(256), 0, stream>>>(ctrl, sel, anchors, bbox, boxes, N);

  if (ws_size >= (size_t)OFF_MAT + MAT_BYTES) {
    suppmat_kernel<<<dim3((SWORDS * (SWORDS + 1) / 2) * NB), dim3(256), 0, stream>>>(boxes, mat);
    nmsscan_kernel<<<dim3(NB), dim3(64), 0, stream>>>(ctrl, boxes, mat, out);
  } else {
    nms_kernel<<<dim3(NB), dim3(1024), 0, stream>>>(boxes, out);
  }
}

// Round 15
// 136.373 us; speedup vs baseline: 1.7571x; 1.0162x over previous
//
#include <hip/hip_runtime.h>

#pragma clang fp contract(off)

#define NB 8
#define KSEL 6000
#define KPAD 6016
#define PROP 1000
#define NTILE 94
#define RMAX 2048
#define RTILES 32
#define SWORDS 32
#define EQ2CAP 262144

// ws layout (bytes)
#define OFF_HIST1 0u          // 8*4096*4 = 131072
#define OFF_CTRL  131072u     // 512 -> 131584
#define OFF_SEL   131584u     // 8*6016*8 = 385024 -> 516608
#define OFF_EQ2   516608u     // 8*262144*8 = 16777216 -> 17293824
#define OFF_BOX   17293824u   // 8*6016*16 = 770048 -> 18063872
#define OFF_MAT   18063872u   // 8*2048*32*8 = 4194304 -> 22258176
#define MAT_BYTES 4194304ull

struct Ctrl {
  unsigned t1, rem1, selCount, eqCount, total;
  unsigned pad[11];
};

__global__ __launch_bounds__(256) void zero_kernel(unsigned* p, int n) {
  int i = blockIdx.x * 256 + threadIdx.x;
  if (i < n) p[i] = 0u;
}

// Pass 1: 4096-bin histogram of top-12 bits of fg scores; float4 loads (2 elems each).
__global__ __launch_bounds__(256) void hist12_kernel(const float* __restrict__ probs,
                                                     unsigned* __restrict__ hist, int N) {
  __shared__ unsigned lh[4096];
  const int b = blockIdx.y;
  for (int k = threadIdx.x; k < 4096; k += 256) lh[k] = 0u;
  __syncthreads();
  const int start = blockIdx.x * 2048;
  const int end = min(start + 2048, N);
#pragma unroll
  for (int j = 0; j < 4; ++j) {
    const int i = start + j * 512 + (int)threadIdx.x * 2;
    if (i < end) {
      const float4 p2 = *(const float4*)(probs + ((size_t)b * N + i) * 2);
      atomicAdd(&lh[__float_as_uint(p2.y) >> 20], 1u);
      if (i + 1 < end) atomicAdd(&lh[__float_as_uint(p2.w) >> 20], 1u);
    }
  }
  __syncthreads();
  for (int k = threadIdx.x; k < 4096; k += 256) {
    const unsigned v = lh[k];
    if (v) atomicAdd(&hist[b * 4096 + k], v);
  }
}

// one wave per image: descending cumulative scan over 4096 bins -> t1, rem1
__global__ __launch_bounds__(64) void scan12_kernel(const unsigned* __restrict__ hist,
                                                    Ctrl* __restrict__ ctrl) {
  const int b = blockIdx.x;
  const int lane = threadIdx.x;
  const unsigned target = (unsigned)KSEL;
  const unsigned* h = hist + b * 4096;
  const int topbin = 4095 - lane * 64;
  unsigned mysum = 0;
  for (int c = 0; c < 64; c++) mysum += h[topbin - c];
  unsigned cum = mysum;
  for (int off = 1; off < 64; off <<= 1) {
    const unsigned v = __shfl_up(cum, off, 64);
    if (lane >= off) cum += v;
  }
  const unsigned prev = cum - mysum;
  if (prev < target && cum >= target) {
    unsigned c2 = prev;
    for (int c = 0; c < 64; c++) {
      const int bin = topbin - c;
      const unsigned hv = h[bin];
      if (c2 + hv >= target) { ctrl[b].t1 = (unsigned)bin; ctrl[b].rem1 = target - c2; break; }
      c2 += hv;
    }
  }
}

// Pass 2: block-aggregated compaction (verified round 13).
__global__ __launch_bounds__(256) void compact2_kernel(const float* __restrict__ probs,
                                                       Ctrl* __restrict__ ctrl,
                                                       unsigned long long* __restrict__ sel,
                                                       unsigned long long* __restrict__ eq2, int N) {
  __shared__ unsigned long long buf[2048];   // 16 KiB
  __shared__ unsigned s_ngt, s_neq, s_gbase, s_ebase;
  const int b = blockIdx.y;
  const int tid = threadIdx.x;
  const unsigned t1 = ctrl[b].t1;
  const int start = blockIdx.x * 2048;
  const int end = min(start + 2048, N);
  if (tid == 0) { s_ngt = 0u; s_neq = 0u; }
  __syncthreads();
  unsigned bits[8];
  int idxs[8];
#pragma unroll
  for (int j = 0; j < 4; ++j) {
    const int i = start + j * 512 + tid * 2;
    float4 p2 = make_float4(0.f, 0.f, 0.f, 0.f);
    if (i < end) p2 = *(const float4*)(probs + ((size_t)b * N + i) * 2);
    bits[j * 2]     = (i < end) ? __float_as_uint(p2.y) : 0u;
    idxs[j * 2]     = (i < end) ? i : -1;
    bits[j * 2 + 1] = (i + 1 < end) ? __float_as_uint(p2.w) : 0u;
    idxs[j * 2 + 1] = (i + 1 < end) ? (i + 1) : -1;
  }
#pragma unroll
  for (int e = 0; e < 8; ++e) {
    if (idxs[e] >= 0) {
      const unsigned top = bits[e] >> 20;
      if (top > t1) {
        const unsigned p = atomicAdd(&s_ngt, 1u);
        buf[p] = ((unsigned long long)bits[e] << 32) | (unsigned)idxs[e];
      } else if (top == t1) {
        const unsigned p = atomicAdd(&s_neq, 1u);
        buf[2047 - p] = ((unsigned long long)bits[e] << 32) | (unsigned)idxs[e];
      }
    }
  }
  __syncthreads();
  const unsigned ngt = s_ngt, neq = s_neq;
  if (tid == 0 && ngt) s_gbase = atomicAdd(&ctrl[b].selCount, ngt);
  if (tid == 1 && neq) s_ebase = atomicAdd(&ctrl[b].eqCount, neq);
  __syncthreads();
  for (unsigned k = tid; k < ngt; k += 256) {
    const unsigned p = s_gbase + k;
    if (p < (unsigned)KPAD) sel[b * KPAD + p] = buf[k];
  }
  for (unsigned k = tid; k < neq; k += 256) {
    const unsigned p = s_ebase + k;
    if (p < (unsigned)EQ2CAP) eq2[(size_t)b * EQ2CAP + p] = buf[2047 - k];
  }
}

// wave-0 scans over a 1024-bin LDS histogram
__device__ inline void scan1024_desc(const unsigned* h, unsigned target, int lane,
                                     unsigned* outBin, unsigned* outRem) {
  const int topbin = 1023 - lane * 16;
  unsigned mysum = 0;
  for (int c = 0; c < 16; ++c) mysum += h[topbin - c];
  unsigned cum = mysum;
  for (int off = 1; off < 64; off <<= 1) {
    const unsigned v = __shfl_up(cum, off, 64);
    if (lane >= off) cum += v;
  }
  const unsigned prev = cum - mysum;
  if (prev < target && cum >= target) {
    unsigned c2 = prev;
    for (int c = 0; c < 16; ++c) {
      const int bin = topbin - c;
      const unsigned hv = h[bin];
      if (c2 + hv >= target) { *outBin = (unsigned)bin; *outRem = target - c2; break; }
      c2 += hv;
    }
  }
}
__device__ inline void scan1024_asc(const unsigned* h, unsigned target, int lane,
                                    unsigned* outBin, unsigned* outRem) {
  const int botbin = lane * 16;
  unsigned mysum = 0;
  for (int c = 0; c < 16; ++c) mysum += h[botbin + c];
  unsigned cum = mysum;
  for (int off = 1; off < 64; off <<= 1) {
    const unsigned v = __shfl_up(cum, off, 64);
    if (lane >= off) cum += v;
  }
  const unsigned prev = cum - mysum;
  if (prev < target && cum >= target) {
    unsigned c2 = prev;
    for (int c = 0; c < 16; ++c) {
      const int bin = botbin + c;
      const unsigned hv = h[bin];
      if (c2 + hv >= target) { *outBin = (unsigned)bin; *outRem = target - c2; break; }
      c2 += hv;
    }
  }
}

// Tie resolution within the t1 bin (verified round 12/13).
__global__ __launch_bounds__(256) void eqres2_kernel(Ctrl* __restrict__ ctrl,
                                                     const unsigned long long* __restrict__ eq2,
                                                     unsigned long long* __restrict__ sel) {
  __shared__ unsigned h1[1024];
  __shared__ unsigned s_binA, s_remA, s_binB, s_remB, s_binC, s_remC;
  __shared__ unsigned s_pos, s_lcnt;
  __shared__ unsigned s_lidx[256];
  const int b = blockIdx.x;
  const int tid = threadIdx.x, lane = tid & 63, wv = tid >> 6;
  unsigned cnt = ctrl[b].eqCount; if (cnt > (unsigned)EQ2CAP) cnt = EQ2CAP;
  const unsigned rem1 = ctrl[b].rem1;
  const unsigned long long* E = eq2 + (size_t)b * EQ2CAP;

  for (int k = tid; k < 1024; k += 256) h1[k] = 0u;
  __syncthreads();
  for (unsigned k = tid; k < cnt; k += 256)
    atomicAdd(&h1[((unsigned)(E[k] >> 32) >> 10) & 1023u], 1u);
  __syncthreads();
  if (wv == 0) scan1024_desc(h1, rem1, lane, &s_binA, &s_remA);
  __syncthreads();
  const unsigned binA = s_binA, remA = s_remA;
  __syncthreads();
  for (int k = tid; k < 1024; k += 256) h1[k] = 0u;
  __syncthreads();
  for (unsigned k = tid; k < cnt; k += 256) {
    const unsigned bits = (unsigned)(E[k] >> 32);
    if (((bits >> 10) & 1023u) == binA) atomicAdd(&h1[bits & 1023u], 1u);
  }
  __syncthreads();
  if (wv == 0) scan1024_desc(h1, remA, lane, &s_binB, &s_remB);
  __syncthreads();
  const unsigned binB = s_binB, remB = s_remB;
  const unsigned key20 = (binA << 10) | binB;
  __syncthreads();
  for (int k = tid; k < 1024; k += 256) h1[k] = 0u;
  __syncthreads();
  for (unsigned k = tid; k < cnt; k += 256) {
    const unsigned long long r = E[k];
    if (((unsigned)(r >> 32) & 0xFFFFFu) == key20) atomicAdd(&h1[((unsigned)r) >> 8], 1u);
  }
  __syncthreads();
  if (wv == 0) scan1024_asc(h1, remB, lane, &s_binC, &s_remC);
  if (tid == 0) { s_pos = ctrl[b].selCount; s_lcnt = 0u; }
  __syncthreads();
  const unsigned binC = s_binC, remC = s_remC;
  for (unsigned k0 = 0; k0 < cnt; k0 += 256) {
    const unsigned k = k0 + tid;
    bool take = false, lst = false;
    unsigned long long rec = 0ull;
    if (k < cnt) {
      rec = E[k];
      const unsigned bits = (unsigned)(rec >> 32);
      const unsigned k20 = bits & 0xFFFFFu;
      const unsigned idx = (unsigned)rec;
      if ((k20 >> 10) > binA) take = true;
      else if ((k20 >> 10) == binA && (k20 & 1023u) > binB) take = true;
      else if (k20 == key20) {
        if ((idx >> 8) < binC) take = true;
        else if ((idx >> 8) == binC) lst = true;
      }
    }
    const unsigned long long mt = __ballot(take);
    if (mt) {
      const int leader = __builtin_ctzll(mt);
      unsigned base = 0;
      if (lane == leader) base = atomicAdd(&s_pos, (unsigned)__builtin_popcountll(mt));
      base = (unsigned)__shfl((int)base, leader, 64);
      if (take) {
        const int rk = __builtin_popcountll(mt & ((1ull << lane) - 1ull));
        const unsigned p = base + (unsigned)rk;
        if (p < (unsigned)KPAD) sel[b * KPAD + p] = rec;
      }
    }
    if (lst) {
      const unsigned p = atomicAdd(&s_lcnt, 1u);
      if (p < 256u) s_lidx[p] = (unsigned)rec;
    }
  }
  __syncthreads();
  const unsigned lcnt = (s_lcnt < 256u) ? s_lcnt : 256u;
  const unsigned long long thrHi = ((unsigned long long)((ctrl[b].t1 << 20) | key20)) << 32;
  if (tid < (int)lcnt) {
    const unsigned my = s_lidx[tid];
    unsigned rk = 0;
    for (unsigned f = 0; f < lcnt; ++f) rk += (s_lidx[f] < my) ? 1u : 0u;
    if (rk < remC) {
      const unsigned p = atomicAdd(&s_pos, 1u);
      if (p < (unsigned)KPAD) sel[b * KPAD + p] = thrHi | (unsigned long long)my;
    }
  }
  __syncthreads();
  if (tid == 0) ctrl[b].total = s_pos;
}

// Pairwise rank + fused decode (verified).
__global__ __launch_bounds__(256) void rank_kernel(const Ctrl* __restrict__ ctrl,
                                                   const unsigned long long* __restrict__ sel,
                                                   const float* __restrict__ anchors,
                                                   const float* __restrict__ bbox,
                                                   float4* __restrict__ boxes, int N) {
  const int b = blockIdx.x & 7;
  const int it = blockIdx.x >> 3;    // 0..93
  const int tid = threadIdx.x;
  const int wv = tid >> 6, lane = tid & 63;
  __shared__ unsigned long long skey[KPAD];   // 48128 B
  __shared__ unsigned scnt[4][64];
  int total = (int)ctrl[b].total; if (total > KSEL) total = KSEL;
  for (int i = tid; i < KPAD; i += 256) {
    unsigned long long kp = 0ull;
    if (i < total) {
      const unsigned long long e = sel[b * KPAD + i];
      kp = (e & 0xFFFFFFFF00000000ull) | (unsigned long long)(0xFFFFFFFFu - (unsigned)e);
    }
    skey[i] = kp;
  }
  __syncthreads();
  const int me = it * 64 + lane;
  const unsigned long long myk = skey[me];
  const int chunk = KPAD / 4;
  const int lo = wv * chunk;
  unsigned cnt = 0;
#pragma unroll 8
  for (int c = 0; c < chunk; ++c) cnt += (skey[lo + c] > myk) ? 1u : 0u;
  scnt[wv][lane] = cnt;
  __syncthreads();
  if (wv == 0 && me < total) {
    const unsigned rank = scnt[0][lane] + scnt[1][lane] + scnt[2][lane] + scnt[3][lane];
    unsigned idx = 0xFFFFFFFFu - (unsigned)myk;
    if (idx >= (unsigned)N) idx = 0;
    const float4 A = ((const float4*)anchors)[(size_t)b * N + idx];
    const float4 R = ((const float4*)bbox)[(size_t)b * N + idx];
    const float d0 = R.x * 0.1f, d1 = R.y * 0.1f, d2 = R.z * 0.2f, d3 = R.w * 0.2f;
    const float h = A.z - A.x;
    const float w = A.w - A.y;
    const float cy = A.x + 0.5f * h + d0 * h;
    const float cx = A.y + 0.5f * w + d1 * w;
    const float e2 = (float)exp((double)d2);  // correctly-rounded f32 exp
    const float e3 = (float)exp((double)d3);
    const float h2 = h * e2;
    const float w2 = w * e3;
    float y1 = cy - 0.5f * h2;
    float x1 = cx - 0.5f * w2;
    float y2 = y1 + h2;
    float x2 = x1 + w2;
    y1 = fminf(fmaxf(y1, 0.0f), 1.0f);
    x1 = fminf(fmaxf(x1, 0.0f), 1.0f);
    y2 = fminf(fmaxf(y2, 0.0f), 1.0f);
    x2 = fminf(fmaxf(x2, 0.0f), 1.0f);
    boxes[b * KPAD + rank] = make_float4(y1, x1, y2, x2);
  }
}

// ---- suppression matrix, pair-tile decomposition (verified round 14) ----
__global__ __launch_bounds__(256) void suppmat_kernel(const float4* __restrict__ boxes,
                                                      unsigned long long* __restrict__ mat) {
  const int b = blockIdx.x & 7;
  int t = blockIdx.x >> 3;
  int it = 0, rem = SWORDS;
  while (t >= rem) { t -= rem; ++it; rem = SWORDS - it; }
  const int jt = it + t;
  const int wv = threadIdx.x >> 6;
  const int lane = threadIdx.x & 63;
  const float4* gbox = boxes + b * KPAD;
  __shared__ float4 srow[64];
  __shared__ float sarea[64];
  if (threadIdx.x < 64) {
    const float4 v = gbox[it * 64 + threadIdx.x];
    srow[threadIdx.x] = v;
    sarea[threadIdx.x] = (v.z - v.x) * (v.w - v.y);
  }
  const int c = jt * 64 + lane;
  const float4 cv = gbox[c];
  const float ca = (cv.z - cv.x) * (cv.w - cv.y);
  __syncthreads();
  const double M = 0.7000000178813934326171875;
  unsigned long long* obase = mat + ((size_t)b * RMAX + (size_t)it * 64) * SWORDS + jt;
#pragma unroll
  for (int k = 0; k < 16; ++k) {
    const int r = wv * 16 + k;
    const int i = it * 64 + r;
    const float4 hb = srow[r];
    const float ha = sarea[r];
    const float iy1 = fmaxf(hb.x, cv.x);
    const float ix1 = fmaxf(hb.y, cv.y);
    const float iy2 = fminf(hb.z, cv.z);
    const float ix2 = fminf(hb.w, cv.w);
    const float dy = fmaxf(iy2 - iy1, 0.0f);
    const float dx = fmaxf(ix2 - ix1, 0.0f);
    const float inter = dy * dx;
    const float denom = ha + ca - inter + 1e-12f;
    const bool s = (c > i) && ((double)inter >= M * (double)denom);
    const unsigned long long w = __ballot(s);
    if (lane == 0) obase[(size_t)r * SWORDS] = w;
  }
}

// Chunked exact greedy NMS with SPARSE replay + early-issued update loads.
// The 64 update-row loads depend only on `base`, not on the replay result — issue them
// BEFORE the sparse chain so their latency hides under the shfl replay; apply the acc
// select-mask afterwards (registers, statically indexed). Rows >= lim load garbage but
// are masked off by acc (in-bounds within RMAX). Semantics identical to round 14.
__global__ __launch_bounds__(64) void nmsscan_kernel(const Ctrl* __restrict__ ctrl,
                                                     const float4* __restrict__ boxes,
                                                     const unsigned long long* __restrict__ mat,
                                                     float* __restrict__ out) {
  const int b = blockIdx.x;
  const int lane = threadIdx.x;
  int total = (int)ctrl[b].total; if (total > KSEL) total = KSEL;
  const unsigned long long* rmat = mat + (size_t)b * RMAX * SWORDS;  // [row][w]
  const float4* gbox = boxes + b * KPAD;
  float4* outv = (float4*)(out + (size_t)b * PROP * 4);
  __shared__ int s_sel[PROP];
  __shared__ float4 s_hbox[PROP];
  const int lim = (total < RMAX) ? total : RMAX;
  const int nchunks = (lim + 63) >> 6;
  const bool wlane = lane < SWORDS;
  unsigned long long r0 = 0ull;     // removed word `lane` (lanes 0..SWORDS-1)
  int nsel = 0;

  unsigned long long diagN = (lane < lim) ? rmat[(size_t)lane * SWORDS] : 0ull;
  for (int c = 0; c < nchunks && nsel < PROP; ++c) {
    const int base = c << 6;
    const int n = ((lim - base) < 64) ? (lim - base) : 64;
    const unsigned long long diag = diagN;
    // prefetch next chunk's diagonal (independent of the serial chain)
    const int nb2 = base + 64;
    diagN = ((c + 1) < nchunks && (nb2 + lane) < lim)
              ? rmat[(size_t)(nb2 + lane) * SWORDS + (c + 1)] : 0ull;
    // issue update-row loads EARLY (independent of replay; masked by acc later)
    unsigned long long uv[64];
    if (wlane && (c + 1) < nchunks) {
      const unsigned long long* rowbase = rmat + (size_t)base * SWORDS + lane;
#pragma unroll
      for (int r = 0; r < 64; ++r) uv[r] = rowbase[(size_t)r * SWORDS];
    }
    // alive word for this chunk (uniform across lanes)
    unsigned long long aw = ~__shfl(r0, c, 64);
    if (n < 64) aw &= ((1ull << n) - 1ull);
    // sparse chain: only rows with nonzero suppression masks can change aw
    unsigned long long S = __ballot(diag != 0ull);
    while (S) {
      const int s = __builtin_ctzll(S);
      S &= S - 1ull;
      const unsigned long long cm = __shfl(diag, s, 64);
      if ((aw >> s) & 1ull) aw &= ~cm;
    }
    unsigned long long acc = aw;
    // budget truncation: keep earliest
    const int need = PROP - nsel;
    int na = __popcll(acc);
    if (na > need) {
      unsigned long long t2 = acc, a2 = 0ull;
      for (int c2 = 0; c2 < need; ++c2) { a2 |= t2 & (0ull - t2); t2 &= t2 - 1ull; }
      acc = a2; na = need;
    }
    if ((acc >> lane) & 1ull) {
      const int r = __popcll(acc & ((1ull << lane) - 1ull));
      s_sel[nsel + r] = base + lane;
    }
    nsel += na;
    if (nsel >= PROP || c + 1 >= nchunks) continue;
    // removed-set update: select-mask the prefetched rows (registers, no new loads)
    if (wlane) {
      unsigned long long o = 0ull;
#pragma unroll
      for (int r = 0; r < 64; ++r) o |= (((acc >> r) & 1ull) ? uv[r] : 0ull);
      r0 |= o;
    }
  }
  if (nsel < PROP && total > lim) {
    for (int k = lane; k < nsel; k += 64) s_hbox[k] = gbox[s_sel[k]];
    __syncthreads();
    const double M = 0.7000000178813934326171875;
    for (int i2 = lim; i2 < total && nsel < PROP; ++i2) {
      const float4 v = gbox[i2];
      const float a = (v.z - v.x) * (v.w - v.y);
      bool supp = false;
      for (int h = lane; h < nsel; h += 64) {
        const float4 hb = s_hbox[h];
        const float ha = (hb.z - hb.x) * (hb.w - hb.y);
        const float iy1 = fmaxf(hb.x, v.x);
        const float ix1 = fmaxf(hb.y, v.y);
        const float iy2 = fminf(hb.z, v.z);
        const float ix2 = fminf(hb.w, v.w);
        const float dy = fmaxf(iy2 - iy1, 0.0f);
        const float dx = fmaxf(ix2 - ix1, 0.0f);
        const float inter = dy * dx;
        const float denom = ha + a - inter + 1e-12f;
        if ((double)inter >= M * (double)denom) { supp = true; break; }
      }
      if (!__any(supp)) {
        if (lane == 0) { s_sel[nsel] = i2; s_hbox[nsel] = v; }
        ++nsel;
      }
    }
  }
  __syncthreads();
  for (int k = lane; k < PROP; k += 64)
    outv[k] = (k < nsel) ? gbox[s_sel[k]] : make_float4(0.f, 0.f, 0.f, 0.f);
}

// ---- fallback windowed NMS (boxes-only) for small ws ----
__global__ __launch_bounds__(1024) void nms_kernel(const float4* __restrict__ boxes, float* __restrict__ out) {
  const int b = blockIdx.x;
  const int tid = threadIdx.x;
  const int lane = tid & 63;
  const float4* gbox = boxes + b * KPAD;
  float* outB = out + b * (PROP * 4);
  __shared__ unsigned long long smask[94];
  __shared__ int s_widx[64];
  __shared__ float4 s_wbox[64];
  __shared__ float s_wha[64];
  __shared__ int s_cnt, s_nAcc, s_total, s_cursor;
  for (int k = tid; k < 94; k += 1024)
    smask[k] = (k == 93) ? ((1ull << 48) - 1ull) : ~0ull;
  if (tid == 0) { s_cursor = 0; s_total = 0; }
  __syncthreads();
  const double M = 0.7000000178813934326171875;
  for (int round = 0; round < PROP; ++round) {
    if (tid == 0) {
      int cnt = 0;
      const int cur = s_cursor;
      int w = cur >> 6;
      unsigned long long word = (w < 94) ? (smask[w] & (~0ull << (cur & 63))) : 0ull;
      while (cnt < 64) {
        while (word == 0ull && ++w < 94) word = smask[w];
        if (w >= 94) break;
        const int bit = __builtin_ctzll(word);
        word &= word - 1ull;
        s_widx[cnt++] = (w << 6) | bit;
      }
      s_cnt = cnt;
      s_cursor = cnt ? (s_widx[cnt - 1] + 1) : KSEL;
    }
    __syncthreads();
    const int cnt = s_cnt;
    const int tailStart = s_cursor;
    if (cnt == 0) break;
    if (tid < 64) {
      const int j = (lane < cnt) ? s_widx[lane] : -1;
      float4 v = make_float4(0.f, 0.f, 0.f, 0.f);
      if (j >= 0) v = gbox[j];
      const float a = (v.z - v.x) * (v.w - v.y);
      const int totalOld = s_total;
      unsigned long long aliveW = __ballot(j >= 0);
      unsigned long long acc = 0ull;
      for (int i = 0; i < 64; ++i) {
        const float hx = __shfl(v.x, i), hy = __shfl(v.y, i);
        const float hz = __shfl(v.z, i), hw = __shfl(v.w, i);
        const float ha = __shfl(a, i);
        bool s = false;
        if (j >= 0 && lane > i) {
          const float iy1 = fmaxf(hx, v.x);
          const float ix1 = fmaxf(hy, v.y);
          const float iy2 = fminf(hz, v.z);
          const float ix2 = fminf(hw, v.w);
          const float dy = fmaxf(iy2 - iy1, 0.0f);
          const float dx = fmaxf(ix2 - ix1, 0.0f);
          const float inter = dy * dx;
          const float denom = ha + a - inter + 1e-12f;
          s = ((double)inter >= M * (double)denom);
        }
        const unsigned long long m = __ballot(s);
        if (aliveW & (1ull << i)) { acc |= 1ull << i; aliveW &= ~m; }
      }
      const int need = PROP - totalOld;
      int na = __popcll(acc);
      if (na > need) {
        unsigned long long t = acc, a2 = 0ull;
        for (int c2 = 0; c2 < need; ++c2) { a2 |= t & (0ull - t); t &= t - 1ull; }
        acc = a2; na = need;
      }
      if ((acc >> lane) & 1ull) {
        const int r = __popcll(acc & ((1ull << lane) - 1ull));
        float* o = outB + (size_t)(totalOld + r) * 4;
        o[0] = v.x; o[1] = v.y; o[2] = v.z; o[3] = v.w;
        s_wbox[r] = v; s_wha[r] = a;
      }
      if (lane == 0) { s_nAcc = na; s_total = totalOld + na; }
      if (j >= 0) atomicAnd(&smask[j >> 6], ~(1ull << (j & 63)));
    }
    __syncthreads();
    const int total = s_total;
    const int nAcc = s_nAcc;
    if (total >= PROP) break;
    for (int j = tailStart + tid; j < KSEL; j += 1024) {
      if (!((smask[j >> 6] >> (j & 63)) & 1ull)) continue;
      const float4 v = gbox[j];
      const float a = (v.z - v.x) * (v.w - v.y);
      bool supp = false;
      for (int r = 0; r < nAcc; ++r) {
        const float4 hb = s_wbox[r];
        const float ha = s_wha[r];
        const float iy1 = fmaxf(hb.x, v.x);
        const float ix1 = fmaxf(hb.y, v.y);
        const float iy2 = fminf(hb.z, v.z);
        const float ix2 = fminf(hb.w, v.w);
        const float dy = fmaxf(iy2 - iy1, 0.0f);
        const float dx = fmaxf(ix2 - ix1, 0.0f);
        const float inter = dy * dx;
        const float denom = ha + a - inter + 1e-12f;
        if ((double)inter >= M * (double)denom) { supp = true; break; }
      }
      if (supp) atomicAnd(&smask[j >> 6], ~(1ull << (j & 63)));
    }
    __syncthreads();
  }
  const int written = s_total;
  for (int u = written * 4 + tid; u < PROP * 4; u += 1024) outB[u] = 0.0f;
}

extern "C" void kernel_launch(void* const* d_in, const int* in_sizes, int n_in,
                              void* d_out, int out_size, void* d_ws, size_t ws_size,
                              hipStream_t stream) {
  (void)n_in; (void)out_size;
  const float* probs = (const float*)d_in[0];
  const float* bbox = (const float*)d_in[1];
  const float* anchors = (const float*)d_in[2];
  float* out = (float*)d_out;
  char* ws = (char*)d_ws;
  const int N = in_sizes[0] / (NB * 2);  // 261888

  unsigned* hist1 = (unsigned*)(ws + OFF_HIST1);
  Ctrl* ctrl = (Ctrl*)(ws + OFF_CTRL);
  unsigned long long* sel = (unsigned long long*)(ws + OFF_SEL);
  unsigned long long* eq2 = (unsigned long long*)(ws + OFF_EQ2);
  float4* boxes = (float4*)(ws + OFF_BOX);
  unsigned long long* mat = (unsigned long long*)(ws + OFF_MAT);

  const int zeroN = (int)((OFF_SEL - OFF_HIST1) / 4);  // hist1 + ctrl
  zero_kernel<<<dim3((zeroN + 255) / 256), dim3(256), 0, stream>>>((unsigned*)ws, zeroN);

  const int gx = (N + 2047) / 2048;      // 128
  hist12_kernel<<<dim3(gx, NB), dim3(256), 0, stream>>>(probs, hist1, N);
  scan12_kernel<<<dim3(NB), dim3(64), 0, stream>>>(hist1, ctrl);
  compact2_kernel<<<dim3(gx, NB), dim3(256), 0, stream>>>(probs, ctrl, sel, eq2, N);
  eqres2_kernel<<<dim3(NB), dim3(256), 0, stream>>>(ctrl, eq2, sel);
  rank_kernel<<<dim3(NTILE * NB), dim3(256), 0, stream>>>(ctrl, sel, anchors, bbox, boxes, N);

  if (ws_size >= (size_t)OFF_MAT + MAT_BYTES) {
    suppmat_kernel<<<dim3((SWORDS * (SWORDS + 1) / 2) * NB), dim3(256), 0, stream>>>(boxes, mat);
    nmsscan_kernel<<<dim3(NB), dim3(64), 0, stream>>>(ctrl, boxes, mat, out);
  } else {
    nms_kernel<<<dim3(NB), dim3(1024), 0, stream>>>(boxes, out);
  }
}

// Round 16
// 122.483 us; speedup vs baseline: 1.9563x; 1.1134x over previous
//
#include <hip/hip_runtime.h>

#pragma clang fp contract(off)

#define NB 8
#define KSEL 6000
#define KPAD 6016
#define PROP 1000
#define RMAX 2048
#define SWORDS 32
#define NTILE 94
#define EQ2CAP 262144
#define SUBCAP 1536

// ws layout (bytes)
#define OFF_HIST1 0u          // 8*4096*4 = 131072
#define OFF_CTRL  131072u     // 512 -> 131584
#define OFF_SEL   131584u     // 8*6016*8 = 385024 -> 516608
#define OFF_EQ2   516608u     // 8*262144*8 = 16777216 -> 17293824
#define OFF_BOX   17293824u   // 8*6016*16 = 770048 -> 18063872
#define OFF_MAT   18063872u   // 8*32*2048*8 = 4194304 -> 22258176  (column-major [w][row])
#define MAT_BYTES 4194304ull

struct Ctrl {
  unsigned t1, rem1, selCount, eqCount, total;
  unsigned pad[11];
};

__global__ __launch_bounds__(256) void zero_kernel(unsigned* p, int n) {
  int i = blockIdx.x * 256 + threadIdx.x;
  if (i < n) p[i] = 0u;
}

// Pass 1: 4096-bin histogram of top-12 bits of fg scores; float4 loads (2 elems each).
__global__ __launch_bounds__(256) void hist12_kernel(const float* __restrict__ probs,
                                                     unsigned* __restrict__ hist, int N) {
  __shared__ unsigned lh[4096];
  const int b = blockIdx.y;
  for (int k = threadIdx.x; k < 4096; k += 256) lh[k] = 0u;
  __syncthreads();
  const int start = blockIdx.x * 2048;
  const int end = min(start + 2048, N);
#pragma unroll
  for (int j = 0; j < 4; ++j) {
    const int i = start + j * 512 + (int)threadIdx.x * 2;
    if (i < end) {
      const float4 p2 = *(const float4*)(probs + ((size_t)b * N + i) * 2);
      atomicAdd(&lh[__float_as_uint(p2.y) >> 20], 1u);
      if (i + 1 < end) atomicAdd(&lh[__float_as_uint(p2.w) >> 20], 1u);
    }
  }
  __syncthreads();
  for (int k = threadIdx.x; k < 4096; k += 256) {
    const unsigned v = lh[k];
    if (v) atomicAdd(&hist[b * 4096 + k], v);
  }
}

// one wave per image: descending cumulative scan over 4096 bins -> t1, rem1
__global__ __launch_bounds__(64) void scan12_kernel(const unsigned* __restrict__ hist,
                                                    Ctrl* __restrict__ ctrl) {
  const int b = blockIdx.x;
  const int lane = threadIdx.x;
  const unsigned target = (unsigned)KSEL;
  const unsigned* h = hist + b * 4096;
  const int topbin = 4095 - lane * 64;
  unsigned mysum = 0;
  for (int c = 0; c < 64; c++) mysum += h[topbin - c];
  unsigned cum = mysum;
  for (int off = 1; off < 64; off <<= 1) {
    const unsigned v = __shfl_up(cum, off, 64);
    if (lane >= off) cum += v;
  }
  const unsigned prev = cum - mysum;
  if (prev < target && cum >= target) {
    unsigned c2 = prev;
    for (int c = 0; c < 64; c++) {
      const int bin = topbin - c;
      const unsigned hv = h[bin];
      if (c2 + hv >= target) { ctrl[b].t1 = (unsigned)bin; ctrl[b].rem1 = target - c2; break; }
      c2 += hv;
    }
  }
}

// Pass 2: block-aggregated compaction (verified round 13).
__global__ __launch_bounds__(256) void compact2_kernel(const float* __restrict__ probs,
                                                       Ctrl* __restrict__ ctrl,
                                                       unsigned long long* __restrict__ sel,
                                                       unsigned long long* __restrict__ eq2, int N) {
  __shared__ unsigned long long buf[2048];   // 16 KiB
  __shared__ unsigned s_ngt, s_neq, s_gbase, s_ebase;
  const int b = blockIdx.y;
  const int tid = threadIdx.x;
  const unsigned t1 = ctrl[b].t1;
  const int start = blockIdx.x * 2048;
  const int end = min(start + 2048, N);
  if (tid == 0) { s_ngt = 0u; s_neq = 0u; }
  __syncthreads();
  unsigned bits[8];
  int idxs[8];
#pragma unroll
  for (int j = 0; j < 4; ++j) {
    const int i = start + j * 512 + tid * 2;
    float4 p2 = make_float4(0.f, 0.f, 0.f, 0.f);
    if (i < end) p2 = *(const float4*)(probs + ((size_t)b * N + i) * 2);
    bits[j * 2]     = (i < end) ? __float_as_uint(p2.y) : 0u;
    idxs[j * 2]     = (i < end) ? i : -1;
    bits[j * 2 + 1] = (i + 1 < end) ? __float_as_uint(p2.w) : 0u;
    idxs[j * 2 + 1] = (i + 1 < end) ? (i + 1) : -1;
  }
#pragma unroll
  for (int e = 0; e < 8; ++e) {
    if (idxs[e] >= 0) {
      const unsigned top = bits[e] >> 20;
      if (top > t1) {
        const unsigned p = atomicAdd(&s_ngt, 1u);
        buf[p] = ((unsigned long long)bits[e] << 32) | (unsigned)idxs[e];
      } else if (top == t1) {
        const unsigned p = atomicAdd(&s_neq, 1u);
        buf[2047 - p] = ((unsigned long long)bits[e] << 32) | (unsigned)idxs[e];
      }
    }
  }
  __syncthreads();
  const unsigned ngt = s_ngt, neq = s_neq;
  if (tid == 0 && ngt) s_gbase = atomicAdd(&ctrl[b].selCount, ngt);
  if (tid == 1 && neq) s_ebase = atomicAdd(&ctrl[b].eqCount, neq);
  __syncthreads();
  for (unsigned k = tid; k < ngt; k += 256) {
    const unsigned p = s_gbase + k;
    if (p < (unsigned)KPAD) sel[b * KPAD + p] = buf[k];
  }
  for (unsigned k = tid; k < neq; k += 256) {
    const unsigned p = s_ebase + k;
    if (p < (unsigned)EQ2CAP) eq2[(size_t)b * EQ2CAP + p] = buf[2047 - k];
  }
}

// wave-0 scans over a 1024-bin LDS histogram
__device__ inline void scan1024_desc(const unsigned* h, unsigned target, int lane,
                                     unsigned* outBin, unsigned* outRem) {
  const int topbin = 1023 - lane * 16;
  unsigned mysum = 0;
  for (int c = 0; c < 16; ++c) mysum += h[topbin - c];
  unsigned cum = mysum;
  for (int off = 1; off < 64; off <<= 1) {
    const unsigned v = __shfl_up(cum, off, 64);
    if (lane >= off) cum += v;
  }
  const unsigned prev = cum - mysum;
  if (prev < target && cum >= target) {
    unsigned c2 = prev;
    for (int c = 0; c < 16; ++c) {
      const int bin = topbin - c;
      const unsigned hv = h[bin];
      if (c2 + hv >= target) { *outBin = (unsigned)bin; *outRem = target - c2; break; }
      c2 += hv;
    }
  }
}
__device__ inline void scan1024_asc(const unsigned* h, unsigned target, int lane,
                                    unsigned* outBin, unsigned* outRem) {
  const int botbin = lane * 16;
  unsigned mysum = 0;
  for (int c = 0; c < 16; ++c) mysum += h[botbin + c];
  unsigned cum = mysum;
  for (int off = 1; off < 64; off <<= 1) {
    const unsigned v = __shfl_up(cum, off, 64);
    if (lane >= off) cum += v;
  }
  const unsigned prev = cum - mysum;
  if (prev < target && cum >= target) {
    unsigned c2 = prev;
    for (int c = 0; c < 16; ++c) {
      const int bin = botbin + c;
      const unsigned hv = h[bin];
      if (c2 + hv >= target) { *outBin = (unsigned)bin; *outRem = target - c2; break; }
      c2 += hv;
    }
  }
}

// Tie resolution: level-A radix, then classify pass (>binA written; ==binA to small LDS
// list), then in-LDS full-key rank-select (expected ~8 entries). Fallback to B/C radix
// passes only on sub-list overflow. Selection order == (bits desc, idx asc) exactly.
__global__ __launch_bounds__(256) void eqres2_kernel(Ctrl* __restrict__ ctrl,
                                                     const unsigned long long* __restrict__ eq2,
                                                     unsigned long long* __restrict__ sel) {
  __shared__ unsigned h1[1024];
  __shared__ unsigned long long s_sub[SUBCAP];   // 12 KiB
  __shared__ unsigned s_binA, s_remA, s_binB, s_remB, s_binC, s_remC;
  __shared__ unsigned s_pos, s_subcnt, s_lcnt;
  __shared__ unsigned s_lidx[256];
  const int b = blockIdx.x;
  const int tid = threadIdx.x, lane = tid & 63, wv = tid >> 6;
  unsigned cnt = ctrl[b].eqCount; if (cnt > (unsigned)EQ2CAP) cnt = EQ2CAP;
  const unsigned rem1 = ctrl[b].rem1;
  const unsigned long long* E = eq2 + (size_t)b * EQ2CAP;

  // level A: bits[19:10], descending
  for (int k = tid; k < 1024; k += 256) h1[k] = 0u;
  __syncthreads();
  for (unsigned k = tid; k < cnt; k += 256)
    atomicAdd(&h1[((unsigned)(E[k] >> 32) >> 10) & 1023u], 1u);
  __syncthreads();
  if (wv == 0) scan1024_desc(h1, rem1, lane, &s_binA, &s_remA);
  if (tid == 0) { s_pos = ctrl[b].selCount; s_subcnt = 0u; }
  __syncthreads();
  const unsigned binA = s_binA, remA = s_remA;
  // classify pass: >binA -> sel (aggregated); ==binA -> s_sub
  for (unsigned k0 = 0; k0 < cnt; k0 += 256) {
    const unsigned k = k0 + tid;
    bool take = false, sub = false;
    unsigned long long rec = 0ull;
    if (k < cnt) {
      rec = E[k];
      const unsigned bk = ((unsigned)(rec >> 32) >> 10) & 1023u;
      take = bk > binA;
      sub = bk == binA;
    }
    const unsigned long long mt = __ballot(take);
    if (mt) {
      const int leader = __builtin_ctzll(mt);
      unsigned base = 0;
      if (lane == leader) base = atomicAdd(&s_pos, (unsigned)__builtin_popcountll(mt));
      base = (unsigned)__shfl((int)base, leader, 64);
      if (take) {
        const int rk = __builtin_popcountll(mt & ((1ull << lane) - 1ull));
        const unsigned p = base + (unsigned)rk;
        if (p < (unsigned)KPAD) sel[b * KPAD + p] = rec;
      }
    }
    if (sub) {
      const unsigned p = atomicAdd(&s_subcnt, 1u);
      if (p < (unsigned)SUBCAP) s_sub[p] = rec;
    }
  }
  __syncthreads();
  const unsigned subcnt = s_subcnt;
  const unsigned base = s_pos;
  if (subcnt <= (unsigned)SUBCAP) {
    // fast path: full-key rank-select over the tiny binA list
    for (unsigned e = tid; e < subcnt; e += 256) {
      const unsigned long long re = s_sub[e];
      const unsigned long long ke = (re & 0xFFFFFFFF00000000ull) |
                                    (unsigned long long)(0xFFFFFFFFu - (unsigned)re);
      unsigned rk = 0;
      for (unsigned f = 0; f < subcnt; ++f) {
        const unsigned long long rf = s_sub[f];
        const unsigned long long kf = (rf & 0xFFFFFFFF00000000ull) |
                                      (unsigned long long)(0xFFFFFFFFu - (unsigned)rf);
        rk += (kf > ke) ? 1u : 0u;
      }
      if (rk < remA) sel[b * KPAD + base + rk] = re;
    }
    __syncthreads();
    if (tid == 0) ctrl[b].total = base + remA;
    return;
  }
  // ---- fallback (sub-list overflow): original B/C radix levels over E ----
  for (int k = tid; k < 1024; k += 256) h1[k] = 0u;
  __syncthreads();
  for (unsigned k = tid; k < cnt; k += 256) {
    const unsigned bits = (unsigned)(E[k] >> 32);
    if (((bits >> 10) & 1023u) == binA) atomicAdd(&h1[bits & 1023u], 1u);
  }
  __syncthreads();
  if (wv == 0) scan1024_desc(h1, remA, lane, &s_binB, &s_remB);
  __syncthreads();
  const unsigned binB = s_binB, remB = s_remB;
  const unsigned key20 = (binA << 10) | binB;
  __syncthreads();
  for (int k = tid; k < 1024; k += 256) h1[k] = 0u;
  __syncthreads();
  for (unsigned k = tid; k < cnt; k += 256) {
    const unsigned long long r = E[k];
    if (((unsigned)(r >> 32) & 0xFFFFFu) == key20) atomicAdd(&h1[((unsigned)r) >> 8], 1u);
  }
  __syncthreads();
  if (wv == 0) scan1024_asc(h1, remB, lane, &s_binC, &s_remC);
  if (tid == 0) s_lcnt = 0u;
  __syncthreads();
  const unsigned binC = s_binC, remC = s_remC;
  for (unsigned k0 = 0; k0 < cnt; k0 += 256) {
    const unsigned k = k0 + tid;
    bool take = false, lst = false;
    unsigned long long rec = 0ull;
    if (k < cnt) {
      rec = E[k];
      const unsigned bits = (unsigned)(rec >> 32);
      const unsigned k20 = bits & 0xFFFFFu;
      const unsigned idx = (unsigned)rec;
      if ((k20 >> 10) == binA) {
        if ((k20 & 1023u) > binB) take = true;
        else if (k20 == key20) {
          if ((idx >> 8) < binC) take = true;
          else if ((idx >> 8) == binC) lst = true;
        }
      }
    }
    const unsigned long long mt = __ballot(take);
    if (mt) {
      const int leader = __builtin_ctzll(mt);
      unsigned bs = 0;
      if (lane == leader) bs = atomicAdd(&s_pos, (unsigned)__builtin_popcountll(mt));
      bs = (unsigned)__shfl((int)bs, leader, 64);
      if (take) {
        const int rk = __builtin_popcountll(mt & ((1ull << lane) - 1ull));
        const unsigned p = bs + (unsigned)rk;
        if (p < (unsigned)KPAD) sel[b * KPAD + p] = rec;
      }
    }
    if (lst) {
      const unsigned p = atomicAdd(&s_lcnt, 1u);
      if (p < 256u) s_lidx[p] = (unsigned)rec;
    }
  }
  __syncthreads();
  const unsigned lcnt = (s_lcnt < 256u) ? s_lcnt : 256u;
  const unsigned long long thrHi = ((unsigned long long)((ctrl[b].t1 << 20) | key20)) << 32;
  if (tid < (int)lcnt) {
    const unsigned my = s_lidx[tid];
    unsigned rk = 0;
    for (unsigned f = 0; f < lcnt; ++f) rk += (s_lidx[f] < my) ? 1u : 0u;
    if (rk < remC) {
      const unsigned p = atomicAdd(&s_pos, 1u);
      if (p < (unsigned)KPAD) sel[b * KPAD + p] = thrHi | (unsigned long long)my;
    }
  }
  __syncthreads();
  if (tid == 0) ctrl[b].total = s_pos;
}

// Pairwise rank + fused decode (verified).
__global__ __launch_bounds__(256) void rank_kernel(const Ctrl* __restrict__ ctrl,
                                                   const unsigned long long* __restrict__ sel,
                                                   const float* __restrict__ anchors,
                                                   const float* __restrict__ bbox,
                                                   float4* __restrict__ boxes, int N) {
  const int b = blockIdx.x & 7;
  const int it = blockIdx.x >> 3;    // 0..93
  const int tid = threadIdx.x;
  const int wv = tid >> 6, lane = tid & 63;
  __shared__ unsigned long long skey[KPAD];   // 48128 B
  __shared__ unsigned scnt[4][64];
  int total = (int)ctrl[b].total; if (total > KSEL) total = KSEL;
  for (int i = tid; i < KPAD; i += 256) {
    unsigned long long kp = 0ull;
    if (i < total) {
      const unsigned long long e = sel[b * KPAD + i];
      kp = (e & 0xFFFFFFFF00000000ull) | (unsigned long long)(0xFFFFFFFFu - (unsigned)e);
    }
    skey[i] = kp;
  }
  __syncthreads();
  const int me = it * 64 + lane;
  const unsigned long long myk = skey[me];
  const int chunk = KPAD / 4;
  const int lo = wv * chunk;
  unsigned cnt = 0;
#pragma unroll 8
  for (int c = 0; c < chunk; ++c) cnt += (skey[lo + c] > myk) ? 1u : 0u;
  scnt[wv][lane] = cnt;
  __syncthreads();
  if (wv == 0 && me < total) {
    const unsigned rank = scnt[0][lane] + scnt[1][lane] + scnt[2][lane] + scnt[3][lane];
    unsigned idx = 0xFFFFFFFFu - (unsigned)myk;
    if (idx >= (unsigned)N) idx = 0;
    const float4 A = ((const float4*)anchors)[(size_t)b * N + idx];
    const float4 R = ((const float4*)bbox)[(size_t)b * N + idx];
    const float d0 = R.x * 0.1f, d1 = R.y * 0.1f, d2 = R.z * 0.2f, d3 = R.w * 0.2f;
    const float h = A.z - A.x;
    const float w = A.w - A.y;
    const float cy = A.x + 0.5f * h + d0 * h;
    const float cx = A.y + 0.5f * w + d1 * w;
    const float e2 = (float)exp((double)d2);  // correctly-rounded f32 exp
    const float e3 = (float)exp((double)d3);
    const float h2 = h * e2;
    const float w2 = w * e3;
    float y1 = cy - 0.5f * h2;
    float x1 = cx - 0.5f * w2;
    float y2 = y1 + h2;
    float x2 = x1 + w2;
    y1 = fminf(fmaxf(y1, 0.0f), 1.0f);
    x1 = fminf(fmaxf(x1, 0.0f), 1.0f);
    y2 = fminf(fmaxf(y2, 0.0f), 1.0f);
    x2 = fminf(fmaxf(x2, 0.0f), 1.0f);
    boxes[b * KPAD + rank] = make_float4(y1, x1, y2, x2);
  }
}

// ---- suppression matrix, pair-tile decomposition, COLUMN-major [w][row] ----
// mat[((b*SWORDS)+w)*RMAX + row] = columns [w*64,w*64+64) of row `row`; written for
// w >= row>>6. Diagonal word zeroes bits c <= row. Sub-diagonal words uninitialized —
// only ORed into already-tested removed-words (dead). LDS-staged coalesced output.
__global__ __launch_bounds__(256) void suppmat_kernel(const float4* __restrict__ boxes,
                                                      unsigned long long* __restrict__ mat) {
  const int b = blockIdx.x & 7;
  int t = blockIdx.x >> 3;
  int it = 0, rem = SWORDS;
  while (t >= rem) { t -= rem; ++it; rem = SWORDS - it; }
  const int jt = it + t;
  const int wv = threadIdx.x >> 6;
  const int lane = threadIdx.x & 63;
  const float4* gbox = boxes + b * KPAD;
  __shared__ float4 srow[64];
  __shared__ float sarea[64];
  __shared__ unsigned long long wrow[64];
  if (threadIdx.x < 64) {
    const float4 v = gbox[it * 64 + threadIdx.x];
    srow[threadIdx.x] = v;
    sarea[threadIdx.x] = (v.z - v.x) * (v.w - v.y);
  }
  const int c = jt * 64 + lane;
  const float4 cv = gbox[c];
  const float ca = (cv.z - cv.x) * (cv.w - cv.y);
  __syncthreads();
  const double M = 0.7000000178813934326171875;
#pragma unroll
  for (int k = 0; k < 16; ++k) {
    const int r = wv * 16 + k;
    const int i = it * 64 + r;
    const float4 hb = srow[r];
    const float ha = sarea[r];
    const float iy1 = fmaxf(hb.x, cv.x);
    const float ix1 = fmaxf(hb.y, cv.y);
    const float iy2 = fminf(hb.z, cv.z);
    const float ix2 = fminf(hb.w, cv.w);
    const float dy = fmaxf(iy2 - iy1, 0.0f);
    const float dx = fmaxf(ix2 - ix1, 0.0f);
    const float inter = dy * dx;
    const float denom = ha + ca - inter + 1e-12f;
    const bool s = (c > i) && ((double)inter >= M * (double)denom);
    const unsigned long long w = __ballot(s);
    if (lane == 0) wrow[r] = w;
  }
  __syncthreads();
  if (threadIdx.x < 64)
    mat[((size_t)(b * SWORDS) + jt) * RMAX + (size_t)it * 64 + threadIdx.x] = wrow[threadIdx.x];
}

// Chunked exact greedy NMS, SPARSE replay, column-major matrix.
// Diag read: coalesced across lanes. Update: lane w reads 512 B CONTIGUOUS
// (32 x ulonglong2) — 8 cache lines instead of 64 — select-masked by acc.
__global__ __launch_bounds__(64) void nmsscan_kernel(const Ctrl* __restrict__ ctrl,
                                                     const float4* __restrict__ boxes,
                                                     const unsigned long long* __restrict__ mat,
                                                     float* __restrict__ out) {
  const int b = blockIdx.x;
  const int lane = threadIdx.x;
  int total = (int)ctrl[b].total; if (total > KSEL) total = KSEL;
  const unsigned long long* cmat = mat + (size_t)(b * SWORDS) * RMAX;  // [w][row]
  const float4* gbox = boxes + b * KPAD;
  float4* outv = (float4*)(out + (size_t)b * PROP * 4);
  __shared__ int s_sel[PROP];
  __shared__ float4 s_hbox[PROP];
  const int lim = (total < RMAX) ? total : RMAX;
  const int nchunks = (lim + 63) >> 6;
  const bool wlane = lane < SWORDS;
  unsigned long long r0 = 0ull;     // removed word `lane` (lanes 0..SWORDS-1)
  int nsel = 0;

  // prefetch chunk 0 diagonal: mat[w=0][row=lane], coalesced
  unsigned long long diagN = (lane < lim) ? cmat[lane] : 0ull;
  for (int c = 0; c < nchunks && nsel < PROP; ++c) {
    const int base = c << 6;
    const int n = ((lim - base) < 64) ? (lim - base) : 64;
    const unsigned long long diag = diagN;
    // prefetch next chunk's diagonal (independent of the serial chain)
    const int nb2 = base + 64;
    diagN = ((c + 1) < nchunks && (nb2 + lane) < lim)
              ? cmat[(size_t)(c + 1) * RMAX + nb2 + lane] : 0ull;
    // alive word for this chunk (uniform across lanes)
    unsigned long long aw = ~__shfl(r0, c, 64);
    if (n < 64) aw &= ((1ull << n) - 1ull);
    // sparse chain: only rows with nonzero suppression masks can change aw
    unsigned long long S = __ballot(diag != 0ull);
    while (S) {
      const int s = __builtin_ctzll(S);
      S &= S - 1ull;
      const unsigned long long cm = __shfl(diag, s, 64);
      if ((aw >> s) & 1ull) aw &= ~cm;
    }
    unsigned long long acc = aw;
    // budget truncation: keep earliest
    const int need = PROP - nsel;
    int na = __popcll(acc);
    if (na > need) {
      unsigned long long t2 = acc, a2 = 0ull;
      for (int c2 = 0; c2 < need; ++c2) { a2 |= t2 & (0ull - t2); t2 &= t2 - 1ull; }
      acc = a2; na = need;
    }
    if ((acc >> lane) & 1ull) {
      const int r = __popcll(acc & ((1ull << lane) - 1ull));
      s_sel[nsel + r] = base + lane;
    }
    nsel += na;
    if (nsel >= PROP || c + 1 >= nchunks) continue;
    // removed-set update: contiguous 512B per lane, select-masked. Sub-diagonal
    // garbage (lane < c) lands only in already-tested removed words — dead.
    if (wlane) {
      const ulonglong2* ub = (const ulonglong2*)(cmat + (size_t)lane * RMAX + base);
      unsigned long long o = 0ull;
#pragma unroll
      for (int g = 0; g < 32; ++g) {
        const ulonglong2 v = ub[g];
        o |= (((acc >> (2 * g)) & 1ull) ? v.x : 0ull);
        o |= (((acc >> (2 * g + 1)) & 1ull) ? v.y : 0ull);
      }
      r0 |= o;
    }
  }
  if (nsel < PROP && total > lim) {
    for (int k = lane; k < nsel; k += 64) s_hbox[k] = gbox[s_sel[k]];
    __syncthreads();
    const double M = 0.7000000178813934326171875;
    for (int i2 = lim; i2 < total && nsel < PROP; ++i2) {
      const float4 v = gbox[i2];
      const float a = (v.z - v.x) * (v.w - v.y);
      bool supp = false;
      for (int h = lane; h < nsel; h += 64) {
        const float4 hb = s_hbox[h];
        const float ha = (hb.z - hb.x) * (hb.w - hb.y);
        const float iy1 = fmaxf(hb.x, v.x);
        const float ix1 = fmaxf(hb.y, v.y);
        const float iy2 = fminf(hb.z, v.z);
        const float ix2 = fminf(hb.w, v.w);
        const float dy = fmaxf(iy2 - iy1, 0.0f);
        const float dx = fmaxf(ix2 - ix1, 0.0f);
        const float inter = dy * dx;
        const float denom = ha + a - inter + 1e-12f;
        if ((double)inter >= M * (double)denom) { supp = true; break; }
      }
      if (!__any(supp)) {
        if (lane == 0) { s_sel[nsel] = i2; s_hbox[nsel] = v; }
        ++nsel;
      }
    }
  }
  __syncthreads();
  for (int k = lane; k < PROP; k += 64)
    outv[k] = (k < nsel) ? gbox[s_sel[k]] : make_float4(0.f, 0.f, 0.f, 0.f);
}

// ---- fallback windowed NMS (boxes-only) for small ws ----
__global__ __launch_bounds__(1024) void nms_kernel(const float4* __restrict__ boxes, float* __restrict__ out) {
  const int b = blockIdx.x;
  const int tid = threadIdx.x;
  const int lane = tid & 63;
  const float4* gbox = boxes + b * KPAD;
  float* outB = out + b * (PROP * 4);
  __shared__ unsigned long long smask[94];
  __shared__ int s_widx[64];
  __shared__ float4 s_wbox[64];
  __shared__ float s_wha[64];
  __shared__ int s_cnt, s_nAcc, s_total, s_cursor;
  for (int k = tid; k < 94; k += 1024)
    smask[k] = (k == 93) ? ((1ull << 48) - 1ull) : ~0ull;
  if (tid == 0) { s_cursor = 0; s_total = 0; }
  __syncthreads();
  const double M = 0.7000000178813934326171875;
  for (int round = 0; round < PROP; ++round) {
    if (tid == 0) {
      int cnt = 0;
      const int cur = s_cursor;
      int w = cur >> 6;
      unsigned long long word = (w < 94) ? (smask[w] & (~0ull << (cur & 63))) : 0ull;
      while (cnt < 64) {
        while (word == 0ull && ++w < 94) word = smask[w];
        if (w >= 94) break;
        const int bit = __builtin_ctzll(word);
        word &= word - 1ull;
        s_widx[cnt++] = (w << 6) | bit;
      }
      s_cnt = cnt;
      s_cursor = cnt ? (s_widx[cnt - 1] + 1) : KSEL;
    }
    __syncthreads();
    const int cnt = s_cnt;
    const int tailStart = s_cursor;
    if (cnt == 0) break;
    if (tid < 64) {
      const int j = (lane < cnt) ? s_widx[lane] : -1;
      float4 v = make_float4(0.f, 0.f, 0.f, 0.f);
      if (j >= 0) v = gbox[j];
      const float a = (v.z - v.x) * (v.w - v.y);
      const int totalOld = s_total;
      unsigned long long aliveW = __ballot(j >= 0);
      unsigned long long acc = 0ull;
      for (int i = 0; i < 64; ++i) {
        const float hx = __shfl(v.x, i), hy = __shfl(v.y, i);
        const float hz = __shfl(v.z, i), hw = __shfl(v.w, i);
        const float ha = __shfl(a, i);
        bool s = false;
        if (j >= 0 && lane > i) {
          const float iy1 = fmaxf(hx, v.x);
          const float ix1 = fmaxf(hy, v.y);
          const float iy2 = fminf(hz, v.z);
          const float ix2 = fminf(hw, v.w);
          const float dy = fmaxf(iy2 - iy1, 0.0f);
          const float dx = fmaxf(ix2 - ix1, 0.0f);
          const float inter = dy * dx;
          const float denom = ha + a - inter + 1e-12f;
          s = ((double)inter >= M * (double)denom);
        }
        const unsigned long long m = __ballot(s);
        if (aliveW & (1ull << i)) { acc |= 1ull << i; aliveW &= ~m; }
      }
      const int need = PROP - totalOld;
      int na = __popcll(acc);
      if (na > need) {
        unsigned long long t = acc, a2 = 0ull;
        for (int c2 = 0; c2 < need; ++c2) { a2 |= t & (0ull - t); t &= t - 1ull; }
        acc = a2; na = need;
      }
      if ((acc >> lane) & 1ull) {
        const int r = __popcll(acc & ((1ull << lane) - 1ull));
        float* o = outB + (size_t)(totalOld + r) * 4;
        o[0] = v.x; o[1] = v.y; o[2] = v.z; o[3] = v.w;
        s_wbox[r] = v; s_wha[r] = a;
      }
      if (lane == 0) { s_nAcc = na; s_total = totalOld + na; }
      if (j >= 0) atomicAnd(&smask[j >> 6], ~(1ull << (j & 63)));
    }
    __syncthreads();
    const int total = s_total;
    const int nAcc = s_nAcc;
    if (total >= PROP) break;
    for (int j = tailStart + tid; j < KSEL; j += 1024) {
      if (!((smask[j >> 6] >> (j & 63)) & 1ull)) continue;
      const float4 v = gbox[j];
      const float a = (v.z - v.x) * (v.w - v.y);
      bool supp = false;
      for (int r = 0; r < nAcc; ++r) {
        const float4 hb = s_wbox[r];
        const float ha = s_wha[r];
        const float iy1 = fmaxf(hb.x, v.x);
        const float ix1 = fmaxf(hb.y, v.y);
        const float iy2 = fminf(hb.z, v.z);
        const float ix2 = fminf(hb.w, v.w);
        const float dy = fmaxf(iy2 - iy1, 0.0f);
        const float dx = fmaxf(ix2 - ix1, 0.0f);
        const float inter = dy * dx;
        const float denom = ha + a - inter + 1e-12f;
        if ((double)inter >= M * (double)denom) { supp = true; break; }
      }
      if (supp) atomicAnd(&smask[j >> 6], ~(1ull << (j & 63)));
    }
    __syncthreads();
  }
  const int written = s_total;
  for (int u = written * 4 + tid; u < PROP * 4; u += 1024) outB[u] = 0.0f;
}

extern "C" void kernel_launch(void* const* d_in, const int* in_sizes, int n_in,
                              void* d_out, int out_size, void* d_ws, size_t ws_size,
                              hipStream_t stream) {
  (void)n_in; (void)out_size;
  const float* probs = (const float*)d_in[0];
  const float* bbox = (const float*)d_in[1];
  const float* anchors = (const float*)d_in[2];
  float* out = (float*)d_out;
  char* ws = (char*)d_ws;
  const int N = in_sizes[0] / (NB * 2);  // 261888

  unsigned* hist1 = (unsigned*)(ws + OFF_HIST1);
  Ctrl* ctrl = (Ctrl*)(ws + OFF_CTRL);
  unsigned long long* sel = (unsigned long long*)(ws + OFF_SEL);
  unsigned long long* eq2 = (unsigned long long*)(ws + OFF_EQ2);
  float4* boxes = (float4*)(ws + OFF_BOX);
  unsigned long long* mat = (unsigned long long*)(ws + OFF_MAT);

  const int zeroN = (int)((OFF_SEL - OFF_HIST1) / 4);  // hist1 + ctrl
  zero_kernel<<<dim3((zeroN + 255) / 256), dim3(256), 0, stream>>>((unsigned*)ws, zeroN);

  const int gx = (N + 2047) / 2048;      // 128
  hist12_kernel<<<dim3(gx, NB), dim3(256), 0, stream>>>(probs, hist1, N);
  scan12_kernel<<<dim3(NB), dim3(64), 0, stream>>>(hist1, ctrl);
  compact2_kernel<<<dim3(gx, NB), dim3(256), 0, stream>>>(probs, ctrl, sel, eq2, N);
  eqres2_kernel<<<dim3(NB), dim3(256), 0, stream>>>(ctrl, eq2, sel);
  rank_kernel<<<dim3(NTILE * NB), dim3(256), 0, stream>>>(ctrl, sel, anchors, bbox, boxes, N);

  if (ws_size >= (size_t)OFF_MAT + MAT_BYTES) {
    suppmat_kernel<<<dim3((SWORDS * (SWORDS + 1) / 2) * NB), dim3(256), 0, stream>>>(boxes, mat);
    nmsscan_kernel<<<dim3(NB), dim3(64), 0, stream>>>(ctrl, boxes, mat, out);
  } else {
    nms_kernel<<<dim3(NB), dim3(1024), 0, stream>>>(boxes, out);
  }
}